// Round 9
// baseline (120.131 us; speedup 1.0000x reference)
//
#include <hip/hip_runtime.h>
#include <hip/hip_bf16.h>

#define BATCH 8
#define CIN   64
#define COUT  64
#define HH    128
#define WW    128
#define HW    (HH * WW)
#define OFFC  18
#define KK    9

typedef __attribute__((ext_vector_type(8))) short short8;
typedef __attribute__((ext_vector_type(8))) unsigned short ushort8;
typedef __attribute__((ext_vector_type(4))) float f32x4;

__device__ __forceinline__ float bf2f(unsigned short u) {
    return __builtin_bit_cast(float, ((unsigned int)u) << 16);
}
__device__ __forceinline__ short f2bf(float v) {
    __hip_bfloat16 h = __float2bfloat16(v);
    return __builtin_bit_cast(short, h);
}
__device__ __forceinline__ unsigned f2h(float v) {
    return (unsigned)__builtin_bit_cast(unsigned short, (_Float16)v);
}
__device__ __forceinline__ float h2f(unsigned bits) {
    return (float)__builtin_bit_cast(_Float16, (unsigned short)(bits & 0xFFFF));
}

// ------- Kernel X: x (b,c,h,w) f32 -> xT (b,h,w,c) bf16, one (b,ho) row per block -------
__global__ __launch_bounds__(256) void to_chlast_k(
    const float* __restrict__ x, unsigned short* __restrict__ xT)
{
    __shared__ unsigned short t[128 * 72];
    int blk = blockIdx.x;                    // b*HH + ho
    int ho = blk & (HH - 1);
    int b  = blk >> 7;
    int tid = threadIdx.x;

    const float* xr = x + (size_t)b * CIN * HW + ho * WW;
    for (int i = tid; i < 2048; i += 256) {
        int c = i >> 5, w4 = (i & 31) * 4;
        float4 v = *(const float4*)(xr + (size_t)c * HW + w4);
        t[(w4 + 0) * 72 + c] = (unsigned short)f2bf(v.x);
        t[(w4 + 1) * 72 + c] = (unsigned short)f2bf(v.y);
        t[(w4 + 2) * 72 + c] = (unsigned short)f2bf(v.z);
        t[(w4 + 3) * 72 + c] = (unsigned short)f2bf(v.w);
    }
    __syncthreads();

    unsigned short* orow = xT + (size_t)blk * WW * 64;
    for (int j = tid; j < 1024; j += 256) {
        int w = j >> 3, c8 = (j & 7) * 8;
        *(ushort8*)(orow + w * 64 + c8) = *(const ushort8*)(t + w * 72 + c8);
    }
}

// ------- Kernel B: w_deform -> bf16 B-fragments wf[kk][nt(4)][lane][8] -------
__global__ __launch_bounds__(256) void build_wfrag_k(
    const float* __restrict__ wd, unsigned short* __restrict__ wf)
{
    int idx = blockIdx.x * 256 + threadIdx.x;
    int ck = idx % 576;
    int o  = idx / 576;
    int c = ck & 63, k = ck >> 6;
    float v = wd[o * 576 + c * 9 + k];
    int kk = ck >> 5, nt = o >> 4;
    int lane = (o & 15) | (((ck >> 3) & 3) << 4);
    int j = ck & 7;
    wf[((kk * 4 + nt) * 64 + lane) * 8 + j] = (unsigned short)f2bf(v);
}

// ------- Kernel B2: w_offset -> bf16 B-fragments wfo[kk][nt(2)][lane][8], N pad 18->32 -------
__global__ __launch_bounds__(256) void build_wfo_k(
    const float* __restrict__ wo, unsigned short* __restrict__ wfo)
{
    int idx = blockIdx.x * 256 + threadIdx.x;
    if (idx >= 32 * 576) return;
    int ck = idx % 576;
    int ov = idx / 576;
    int c = ck & 63, tap = ck >> 6;
    float v = (ov < OFFC) ? wo[ov * 576 + c * 9 + tap] : 0.f;
    int kk = ck >> 5, nt = ov >> 4;
    int lane = (ov & 15) | (((ck >> 3) & 3) << 4);
    int j = ck & 7;
    wfo[((kk * 2 + nt) * 64 + lane) * 8 + j] = (unsigned short)f2bf(v);
}

// ---------------- Kernel P: offsets conv (MFMA) + position/weight records ----------------
// Block = one row (128 px), 4 waves x 2 A-tiles. Writes per-(pixel,tap) 16B records:
// .x = idx00 | ddx<<14 | dyflag<<15 ; .y = f16(w00)|f16(w01)<<16 ; .z = f16(w10)|f16(w11)<<16
__global__ __launch_bounds__(256) void pos_build_k(
    const unsigned short* __restrict__ xT,
    const short8* __restrict__ wfo, int4* __restrict__ rec)
{
    __shared__ float offsL[128 * 20];          // 10240 B

    int tid  = threadIdx.x;
    int blk  = blockIdx.x;                     // ho*8 + b
    int b    = blk & 7;
    int ho   = blk >> 3;

    const unsigned short* pT = xT + (size_t)b * HW * 64;

    int lane  = tid & 63;
    int wave  = tid >> 6;
    int prow  = lane & 15;
    int khalf = lane >> 4;
    int px0   = wave * 32 + prow;
    int px1   = px0 + 16;

    // ---- phase A: offsets = conv3x3(x, w_offset) via MFMA (2 pixel-tiles) ----
    {
        f32x4 oa00 = {0.f,0.f,0.f,0.f}, oa01 = {0.f,0.f,0.f,0.f};
        f32x4 oa10 = {0.f,0.f,0.f,0.f}, oa11 = {0.f,0.f,0.f,0.f};
        #pragma unroll
        for (int kk = 0; kk < 18; ++kk) {
            int tap = kk >> 1;
            int y   = ho + tap / 3 - 1;
            int dx  = tap % 3 - 1;
            int c0  = ((kk & 1) << 5) + (khalf << 3);
            short8 a0 = {0,0,0,0,0,0,0,0};
            short8 a1 = {0,0,0,0,0,0,0,0};
            int xw0 = px0 + dx, xw1 = px1 + dx;
            if ((unsigned)y < HH && (unsigned)xw0 < WW)
                a0 = *(const short8*)(pT + (((size_t)(y * WW + xw0)) << 6) + c0);
            if ((unsigned)y < HH && (unsigned)xw1 < WW)
                a1 = *(const short8*)(pT + (((size_t)(y * WW + xw1)) << 6) + c0);
            short8 b0 = wfo[(kk * 2 + 0) * 64 + lane];
            short8 b1 = wfo[(kk * 2 + 1) * 64 + lane];
            oa00 = __builtin_amdgcn_mfma_f32_16x16x32_bf16(a0, b0, oa00, 0, 0, 0);
            oa01 = __builtin_amdgcn_mfma_f32_16x16x32_bf16(a0, b1, oa01, 0, 0, 0);
            oa10 = __builtin_amdgcn_mfma_f32_16x16x32_bf16(a1, b0, oa10, 0, 0, 0);
            oa11 = __builtin_amdgcn_mfma_f32_16x16x32_bf16(a1, b1, oa11, 0, 0, 0);
        }
        int ocol = lane & 15;
        int pix0 = wave * 32 + khalf * 4;
        #pragma unroll
        for (int r = 0; r < 4; ++r) {
            offsL[(pix0 + r) * 20 + ocol]      = oa00[r];
            offsL[(pix0 + 16 + r) * 20 + ocol] = oa10[r];
        }
        if (ocol < 2) {
            #pragma unroll
            for (int r = 0; r < 4; ++r) {
                offsL[(pix0 + r) * 20 + 16 + ocol]      = oa01[r];
                offsL[(pix0 + 16 + r) * 20 + 16 + ocol] = oa11[r];
            }
        }
    }
    __syncthreads();

    // ---- phase 0: 128 px x 9 taps -> packed records to global ----
    int4* rrow = rec + ((size_t)(b * HH + ho) * WW) * 9;
    for (int e = tid; e < 1152; e += 256) {
        int p = e / 9, k = e - p * 9;
        float dy = offsL[p * 20 + 2 * k];
        float dx = offsL[p * 20 + 2 * k + 1];
        float yy = (float)(ho - 1 + k / 3) + dy;
        float xx = (float)(p - 1 + k % 3) + dx;
        float y0 = floorf(yy), x0 = floorf(xx);
        float wy1 = yy - y0, wx1 = xx - x0;
        float wy0 = 1.f - wy1, wx0 = 1.f - wx1;
        bool valid = (yy > -1.f) && (yy < (float)HH) && (xx > -1.f) && (xx < (float)WW);
        int y0i = (int)y0, x0i = (int)x0;
        bool iy0 = (unsigned)y0i < HH, iy1 = (unsigned)(y0i + 1) < HH;
        bool ix0 = (unsigned)x0i < WW, ix1 = (unsigned)(x0i + 1) < WW;
        float m00 = (valid && iy0 && ix0) ? 1.f : 0.f;
        float m01 = (valid && iy0 && ix1) ? 1.f : 0.f;
        float m10 = (valid && iy1 && ix0) ? 1.f : 0.f;
        float m11 = (valid && iy1 && ix1) ? 1.f : 0.f;
        int yc0 = min(max(y0i, 0), HH - 1), yc1 = min(max(y0i + 1, 0), HH - 1);
        int xc0 = min(max(x0i, 0), WW - 1), xc1 = min(max(x0i + 1, 0), WW - 1);
        int idx00 = yc0 * WW + xc0;
        int ddx   = xc1 - xc0;                   // 0 or 1
        int dyf   = yc1 - yc0;                   // 0 or 1
        int4 r;
        r.x = idx00 | (ddx << 14) | (dyf << 15);
        r.y = (int)(f2h(wy0 * wx0 * m00) | (f2h(wy0 * wx1 * m01) << 16));
        r.z = (int)(f2h(wy1 * wx0 * m10) | (f2h(wy1 * wx1 * m11) << 16));
        r.w = 0;
        rrow[e] = r;
    }
}

// ---------------- Kernel M: barrier-free, LDS-free gather + MFMA ----------------
// Block = one row (128 px) x 64 outputs; 4 waves x 2 A-tiles. Per tap: 2 record reads,
// 16 gathers (2 tiles x 4 corners x 2 c-halves) + 8 wf loads, 16 MFMAs. No __syncthreads
// anywhere -> waves pipeline independently; compiler free to deep-schedule loads.
__global__ __launch_bounds__(256) void deform_main2_k(
    const unsigned short* __restrict__ xT,
    const int4* __restrict__ rec,
    const short8* __restrict__ wf, float* __restrict__ out)
{
    int tid  = threadIdx.x;
    int blk  = blockIdx.x;                     // ho*8 + b
    int b    = blk & 7;
    int ho   = blk >> 3;

    const unsigned short* pT = xT + (size_t)b * HW * 64;

    int lane  = tid & 63;
    int wave  = tid >> 6;
    int prow  = lane & 15;
    int khalf = lane >> 4;
    int px0   = wave * 32 + prow;
    int px1   = px0 + 16;

    const int4* recA = rec + ((size_t)(b * HH + ho) * WW + px0) * 9;
    const int4* recB = rec + ((size_t)(b * HH + ho) * WW + px1) * 9;

    f32x4 accA0 = {0.f,0.f,0.f,0.f}, accA1 = {0.f,0.f,0.f,0.f};
    f32x4 accA2 = {0.f,0.f,0.f,0.f}, accA3 = {0.f,0.f,0.f,0.f};
    f32x4 accB0 = {0.f,0.f,0.f,0.f}, accB1 = {0.f,0.f,0.f,0.f};
    f32x4 accB2 = {0.f,0.f,0.f,0.f}, accB3 = {0.f,0.f,0.f,0.f};

    const unsigned short* bp0 = pT + (khalf << 3);       // c-half 0 (ch 0..31 slice)
    const unsigned short* bp1 = bp0 + 32;                // c-half 1 (ch 32..63 slice)

    #pragma unroll 3
    for (int tap = 0; tap < 9; ++tap) {
        int4 rA = recA[tap];
        int4 rB = recB[tap];

        short8 b00 = wf[((2 * tap) * 4 + 0) * 64 + lane];
        short8 b01 = wf[((2 * tap) * 4 + 1) * 64 + lane];
        short8 b02 = wf[((2 * tap) * 4 + 2) * 64 + lane];
        short8 b03 = wf[((2 * tap) * 4 + 3) * 64 + lane];
        short8 b10 = wf[((2 * tap + 1) * 4 + 0) * 64 + lane];
        short8 b11 = wf[((2 * tap + 1) * 4 + 1) * 64 + lane];
        short8 b12 = wf[((2 * tap + 1) * 4 + 2) * 64 + lane];
        short8 b13 = wf[((2 * tap + 1) * 4 + 3) * 64 + lane];

        int iA = rA.x & 0x3FFF, dA = (rA.x >> 14) & 1, yA = ((rA.x >> 15) & 1) << 7;
        int iB = rB.x & 0x3FFF, dB = (rB.x >> 14) & 1, yB = ((rB.x >> 15) & 1) << 7;
        float wA00 = h2f(rA.y), wA01 = h2f((unsigned)rA.y >> 16);
        float wA10 = h2f(rA.z), wA11 = h2f((unsigned)rA.z >> 16);
        float wB00 = h2f(rB.y), wB01 = h2f((unsigned)rB.y >> 16);
        float wB10 = h2f(rB.z), wB11 = h2f((unsigned)rB.z >> 16);

        size_t oA0 = (size_t)iA * 64,           oA1 = (size_t)(iA + dA) * 64;
        size_t oA2 = (size_t)(iA + yA) * 64,    oA3 = (size_t)(iA + yA + dA) * 64;
        size_t oB0 = (size_t)iB * 64,           oB1 = (size_t)(iB + dB) * 64;
        size_t oB2 = (size_t)(iB + yB) * 64,    oB3 = (size_t)(iB + yB + dB) * 64;

        // 16 independent 16B gathers (2 tiles x 4 corners x 2 c-halves)
        ushort8 A0a = *(const ushort8*)(bp0 + oA0), A1a = *(const ushort8*)(bp0 + oA1);
        ushort8 A2a = *(const ushort8*)(bp0 + oA2), A3a = *(const ushort8*)(bp0 + oA3);
        ushort8 A0b = *(const ushort8*)(bp1 + oA0), A1b = *(const ushort8*)(bp1 + oA1);
        ushort8 A2b = *(const ushort8*)(bp1 + oA2), A3b = *(const ushort8*)(bp1 + oA3);
        ushort8 B0a = *(const ushort8*)(bp0 + oB0), B1a = *(const ushort8*)(bp0 + oB1);
        ushort8 B2a = *(const ushort8*)(bp0 + oB2), B3a = *(const ushort8*)(bp0 + oB3);
        ushort8 B0b = *(const ushort8*)(bp1 + oB0), B1b = *(const ushort8*)(bp1 + oB1);
        ushort8 B2b = *(const ushort8*)(bp1 + oB2), B3b = *(const ushort8*)(bp1 + oB3);

        short8 aA0, aB0, aA1, aB1;
        #pragma unroll
        for (int j = 0; j < 8; ++j) {
            float v0 = wA00 * bf2f(A0a[j]) + wA01 * bf2f(A1a[j])
                     + wA10 * bf2f(A2a[j]) + wA11 * bf2f(A3a[j]);
            float v1 = wA00 * bf2f(A0b[j]) + wA01 * bf2f(A1b[j])
                     + wA10 * bf2f(A2b[j]) + wA11 * bf2f(A3b[j]);
            float u0 = wB00 * bf2f(B0a[j]) + wB01 * bf2f(B1a[j])
                     + wB10 * bf2f(B2a[j]) + wB11 * bf2f(B3a[j]);
            float u1 = wB00 * bf2f(B0b[j]) + wB01 * bf2f(B1b[j])
                     + wB10 * bf2f(B2b[j]) + wB11 * bf2f(B3b[j]);
            aA0[j] = f2bf(v0);  aA1[j] = f2bf(v1);
            aB0[j] = f2bf(u0);  aB1[j] = f2bf(u1);
        }
        accA0 = __builtin_amdgcn_mfma_f32_16x16x32_bf16(aA0, b00, accA0, 0, 0, 0);
        accA1 = __builtin_amdgcn_mfma_f32_16x16x32_bf16(aA0, b01, accA1, 0, 0, 0);
        accA2 = __builtin_amdgcn_mfma_f32_16x16x32_bf16(aA0, b02, accA2, 0, 0, 0);
        accA3 = __builtin_amdgcn_mfma_f32_16x16x32_bf16(aA0, b03, accA3, 0, 0, 0);
        accB0 = __builtin_amdgcn_mfma_f32_16x16x32_bf16(aB0, b00, accB0, 0, 0, 0);
        accB1 = __builtin_amdgcn_mfma_f32_16x16x32_bf16(aB0, b01, accB1, 0, 0, 0);
        accB2 = __builtin_amdgcn_mfma_f32_16x16x32_bf16(aB0, b02, accB2, 0, 0, 0);
        accB3 = __builtin_amdgcn_mfma_f32_16x16x32_bf16(aB0, b03, accB3, 0, 0, 0);
        accA0 = __builtin_amdgcn_mfma_f32_16x16x32_bf16(aA1, b10, accA0, 0, 0, 0);
        accA1 = __builtin_amdgcn_mfma_f32_16x16x32_bf16(aA1, b11, accA1, 0, 0, 0);
        accA2 = __builtin_amdgcn_mfma_f32_16x16x32_bf16(aA1, b12, accA2, 0, 0, 0);
        accA3 = __builtin_amdgcn_mfma_f32_16x16x32_bf16(aA1, b13, accA3, 0, 0, 0);
        accB0 = __builtin_amdgcn_mfma_f32_16x16x32_bf16(aB1, b10, accB0, 0, 0, 0);
        accB1 = __builtin_amdgcn_mfma_f32_16x16x32_bf16(aB1, b11, accB1, 0, 0, 0);
        accB2 = __builtin_amdgcn_mfma_f32_16x16x32_bf16(aB1, b12, accB2, 0, 0, 0);
        accB3 = __builtin_amdgcn_mfma_f32_16x16x32_bf16(aB1, b13, accB3, 0, 0, 0);
    }

    // ---- epilogue: direct f32x4 stores (lane holds 4 consecutive pixels per o) ----
    {
        int ocol = lane & 15;
        int pixA = wave * 32 + khalf * 4;
        float* ob = out + ((size_t)b * COUT) * HW + ho * WW;
        f32x4* dst;
        dst = (f32x4*)(ob + (size_t)(0 * 16 + ocol) * HW + pixA);
        dst[0] = accA0;  dst[4] = accB0;
        dst = (f32x4*)(ob + (size_t)(1 * 16 + ocol) * HW + pixA);
        dst[0] = accA1;  dst[4] = accB1;
        dst = (f32x4*)(ob + (size_t)(2 * 16 + ocol) * HW + pixA);
        dst[0] = accA2;  dst[4] = accB2;
        dst = (f32x4*)(ob + (size_t)(3 * 16 + ocol) * HW + pixA);
        dst[0] = accA3;  dst[4] = accB3;
    }
}

extern "C" void kernel_launch(void* const* d_in, const int* in_sizes, int n_in,
                              void* d_out, int out_size, void* d_ws, size_t ws_size,
                              hipStream_t stream)
{
    const float* x    = (const float*)d_in[0];
    const float* woff = (const float*)d_in[1];
    const float* wdef = (const float*)d_in[2];
    float* out  = (float*)d_out;

    unsigned short* wfrag = (unsigned short*)d_ws;          // 73.7 KB
    unsigned short* wfo   = wfrag + 36864;                  // 36.9 KB
    unsigned short* xT    = wfo + 18432;                    // 16.8 MB
    int4* rec = (int4*)(xT + (size_t)BATCH * HW * 64);      // 8*16384*9*16B = 18.9 MB

    hipLaunchKernelGGL(to_chlast_k, dim3(BATCH * HH), dim3(256), 0, stream,
                       x, xT);
    hipLaunchKernelGGL(build_wfrag_k, dim3(COUT * 576 / 256), dim3(256), 0, stream,
                       wdef, wfrag);
    hipLaunchKernelGGL(build_wfo_k, dim3(32 * 576 / 256), dim3(256), 0, stream,
                       woff, wfo);
    hipLaunchKernelGGL(pos_build_k, dim3(HH * 8), dim3(256), 0, stream,
                       xT, (const short8*)wfo, rec);
    hipLaunchKernelGGL(deform_main2_k, dim3(HH * 8), dim3(256), 0, stream,
                       xT, rec, (const short8*)wfrag, out);
}

// Round 10
// 112.618 us; speedup vs baseline: 1.0667x; 1.0667x over previous
//
#include <hip/hip_runtime.h>
#include <hip/hip_bf16.h>

#define BATCH 8
#define CIN   64
#define COUT  64
#define HH    128
#define WW    128
#define HW    (HH * WW)
#define OFFC  18
#define KK    9

typedef __attribute__((ext_vector_type(8))) short short8;
typedef __attribute__((ext_vector_type(8))) unsigned short ushort8;
typedef __attribute__((ext_vector_type(4))) float f32x4;

__device__ __forceinline__ float bf2f(unsigned short u) {
    return __builtin_bit_cast(float, ((unsigned int)u) << 16);
}
__device__ __forceinline__ short f2bf(float v) {
    __hip_bfloat16 h = __float2bfloat16(v);
    return __builtin_bit_cast(short, h);
}
__device__ __forceinline__ unsigned f2h(float v) {
    return (unsigned)__builtin_bit_cast(unsigned short, (_Float16)v);
}
__device__ __forceinline__ float h2f(unsigned bits) {
    return (float)__builtin_bit_cast(_Float16, (unsigned short)(bits & 0xFFFF));
}

// ------- Kernel X: x (b,c,h,w) f32 -> xT (b,h,w,c) bf16 -------
// Grid swizzled b = blk&7 so the XCD that writes a row is the one that reads it.
__global__ __launch_bounds__(256) void to_chlast_k(
    const float* __restrict__ x, unsigned short* __restrict__ xT)
{
    __shared__ unsigned short t[128 * 72];
    int blk = blockIdx.x;                    // ho*8 + b
    int b  = blk & 7;
    int ho = blk >> 3;
    int tid = threadIdx.x;

    const float* xr = x + (size_t)b * CIN * HW + ho * WW;
    for (int i = tid; i < 2048; i += 256) {
        int c = i >> 5, w4 = (i & 31) * 4;
        float4 v = *(const float4*)(xr + (size_t)c * HW + w4);
        t[(w4 + 0) * 72 + c] = (unsigned short)f2bf(v.x);
        t[(w4 + 1) * 72 + c] = (unsigned short)f2bf(v.y);
        t[(w4 + 2) * 72 + c] = (unsigned short)f2bf(v.z);
        t[(w4 + 3) * 72 + c] = (unsigned short)f2bf(v.w);
    }
    __syncthreads();

    unsigned short* orow = xT + (size_t)(b * HH + ho) * WW * 64;
    for (int j = tid; j < 1024; j += 256) {
        int w = j >> 3, c8 = (j & 7) * 8;
        *(ushort8*)(orow + w * 64 + c8) = *(const ushort8*)(t + w * 72 + c8);
    }
}

// ------- Kernel B: w_deform -> bf16 B-fragments wf[kk][nt(4)][lane][8] -------
__global__ __launch_bounds__(256) void build_wfrag_k(
    const float* __restrict__ wd, unsigned short* __restrict__ wf)
{
    int idx = blockIdx.x * 256 + threadIdx.x;
    int ck = idx % 576;
    int o  = idx / 576;
    int c = ck & 63, k = ck >> 6;
    float v = wd[o * 576 + c * 9 + k];
    int kk = ck >> 5, nt = o >> 4;
    int lane = (o & 15) | (((ck >> 3) & 3) << 4);
    int j = ck & 7;
    wf[((kk * 4 + nt) * 64 + lane) * 8 + j] = (unsigned short)f2bf(v);
}

// ------- Kernel B2: w_offset -> bf16 B-fragments wfo[kk][nt(2)][lane][8], N pad 18->32 -------
__global__ __launch_bounds__(256) void build_wfo_k(
    const float* __restrict__ wo, unsigned short* __restrict__ wfo)
{
    int idx = blockIdx.x * 256 + threadIdx.x;
    if (idx >= 32 * 576) return;
    int ck = idx % 576;
    int ov = idx / 576;
    int c = ck & 63, tap = ck >> 6;
    float v = (ov < OFFC) ? wo[ov * 576 + c * 9 + tap] : 0.f;
    int kk = ck >> 5, nt = ov >> 4;
    int lane = (ov & 15) | (((ck >> 3) & 3) << 4);
    int j = ck & 7;
    wfo[((kk * 2 + nt) * 64 + lane) * 8 + j] = (unsigned short)f2bf(v);
}

// ---------------- Kernel C: fully-fused, ZERO-barrier deform conv ----------------
// Block = one row (128 px) x 64 outputs; 4 waves x 32 px (2 A-tiles). Each wave is
// SELF-CONTAINED: phase A (offsets conv MFMA) -> its own offsL slice; phase 0 ->
// its own recL slice; phase 1 tap loop reads only its slices. Producer/consumer
// lanes always in the same wave => no __syncthreads anywhere (lgkmcnt ordering).
// rec stays in LDS (no 18.9MB global stream); output stored NONTEMPORAL so xT
// keeps its per-XCD L2 residency (b = blk&7 -> XCD owns one batch, 2.1MB slice).
__global__ __launch_bounds__(256) void deform_fused2_k(
    const unsigned short* __restrict__ xT,
    const short8* __restrict__ wfo,
    const short8* __restrict__ wf, float* __restrict__ out)
{
    __shared__ float offsL[4][32 * 20];     // 10240 B  [wave][pix][20]
    __shared__ int4  recL[4][288];          // 18432 B  [wave][pix*9+tap]

    int tid  = threadIdx.x;
    int blk  = blockIdx.x;                  // ho*8 + b
    int b    = blk & 7;
    int ho   = blk >> 3;

    const unsigned short* pT = xT + (size_t)b * HW * 64;

    int lane  = tid & 63;
    int wave  = tid >> 6;
    int prow  = lane & 15;
    int khalf = lane >> 4;
    int px0   = wave * 32 + prow;           // global pixel (tile 0)
    int px1   = px0 + 16;                   // tile 1

    // ---- phase A: offsets = conv3x3(x, w_offset) via MFMA, 2 pixel-tiles ----
    {
        f32x4 oa00 = {0.f,0.f,0.f,0.f}, oa01 = {0.f,0.f,0.f,0.f};
        f32x4 oa10 = {0.f,0.f,0.f,0.f}, oa11 = {0.f,0.f,0.f,0.f};
        #pragma unroll
        for (int kk = 0; kk < 18; ++kk) {
            int tap = kk >> 1;
            int y   = ho + tap / 3 - 1;
            int dx  = tap % 3 - 1;
            int c0  = ((kk & 1) << 5) + (khalf << 3);
            short8 a0 = {0,0,0,0,0,0,0,0};
            short8 a1 = {0,0,0,0,0,0,0,0};
            int xw0 = px0 + dx, xw1 = px1 + dx;
            if ((unsigned)y < HH && (unsigned)xw0 < WW)
                a0 = *(const short8*)(pT + (((size_t)(y * WW + xw0)) << 6) + c0);
            if ((unsigned)y < HH && (unsigned)xw1 < WW)
                a1 = *(const short8*)(pT + (((size_t)(y * WW + xw1)) << 6) + c0);
            short8 b0 = wfo[(kk * 2 + 0) * 64 + lane];
            short8 b1 = wfo[(kk * 2 + 1) * 64 + lane];
            oa00 = __builtin_amdgcn_mfma_f32_16x16x32_bf16(a0, b0, oa00, 0, 0, 0);
            oa01 = __builtin_amdgcn_mfma_f32_16x16x32_bf16(a0, b1, oa01, 0, 0, 0);
            oa10 = __builtin_amdgcn_mfma_f32_16x16x32_bf16(a1, b0, oa10, 0, 0, 0);
            oa11 = __builtin_amdgcn_mfma_f32_16x16x32_bf16(a1, b1, oa11, 0, 0, 0);
        }
        // D layout: col = lane&15 = oc, row = khalf*4+r = local pixel (per tile)
        int ocol = lane & 15;
        int pl0  = khalf * 4;
        #pragma unroll
        for (int r = 0; r < 4; ++r) {
            offsL[wave][(pl0 + r) * 20 + ocol]        = oa00[r];
            offsL[wave][(pl0 + 16 + r) * 20 + ocol]   = oa10[r];
        }
        if (ocol < 2) {
            #pragma unroll
            for (int r = 0; r < 4; ++r) {
                offsL[wave][(pl0 + r) * 20 + 16 + ocol]      = oa01[r];
                offsL[wave][(pl0 + 16 + r) * 20 + 16 + ocol] = oa11[r];
            }
        }
    }
    // no barrier: same-wave LDS RAW, compiler inserts lgkmcnt

    // ---- phase 0: this wave's 32 px x 9 taps -> packed records in LDS ----
    for (int e = lane; e < 288; e += 64) {
        int p = e / 9, k = e - p * 9;       // p = local pixel 0..31
        int wo = wave * 32 + p;
        float dy = offsL[wave][p * 20 + 2 * k];
        float dx = offsL[wave][p * 20 + 2 * k + 1];
        float yy = (float)(ho - 1 + k / 3) + dy;
        float xx = (float)(wo - 1 + k % 3) + dx;
        float y0 = floorf(yy), x0 = floorf(xx);
        float wy1 = yy - y0, wx1 = xx - x0;
        float wy0 = 1.f - wy1, wx0 = 1.f - wx1;
        bool valid = (yy > -1.f) && (yy < (float)HH) && (xx > -1.f) && (xx < (float)WW);
        int y0i = (int)y0, x0i = (int)x0;
        bool iy0 = (unsigned)y0i < HH, iy1 = (unsigned)(y0i + 1) < HH;
        bool ix0 = (unsigned)x0i < WW, ix1 = (unsigned)(x0i + 1) < WW;
        float m00 = (valid && iy0 && ix0) ? 1.f : 0.f;
        float m01 = (valid && iy0 && ix1) ? 1.f : 0.f;
        float m10 = (valid && iy1 && ix0) ? 1.f : 0.f;
        float m11 = (valid && iy1 && ix1) ? 1.f : 0.f;
        int yc0 = min(max(y0i, 0), HH - 1), yc1 = min(max(y0i + 1, 0), HH - 1);
        int xc0 = min(max(x0i, 0), WW - 1), xc1 = min(max(x0i + 1, 0), WW - 1);
        int idx00 = yc0 * WW + xc0;
        int ddx   = xc1 - xc0;               // 0 or 1
        int dyf   = yc1 - yc0;               // 0 or 1
        int4 r;
        r.x = idx00 | (ddx << 14) | (dyf << 15);
        r.y = (int)(f2h(wy0 * wx0 * m00) | (f2h(wy0 * wx1 * m01) << 16));
        r.z = (int)(f2h(wy1 * wx0 * m10) | (f2h(wy1 * wx1 * m11) << 16));
        r.w = 0;
        recL[wave][e] = r;
    }
    // no barrier: same-wave producer/consumer

    // ---- phase 1: gather + MFMA, 2 A-tiles sharing B-fragments ----
    f32x4 accA0 = {0.f,0.f,0.f,0.f}, accA1 = {0.f,0.f,0.f,0.f};
    f32x4 accA2 = {0.f,0.f,0.f,0.f}, accA3 = {0.f,0.f,0.f,0.f};
    f32x4 accB0 = {0.f,0.f,0.f,0.f}, accB1 = {0.f,0.f,0.f,0.f};
    f32x4 accB2 = {0.f,0.f,0.f,0.f}, accB3 = {0.f,0.f,0.f,0.f};

    const unsigned short* bp0 = pT + (khalf << 3);
    const unsigned short* bp1 = bp0 + 32;

    #pragma unroll 3
    for (int tap = 0; tap < 9; ++tap) {
        int4 rA = recL[wave][prow * 9 + tap];
        int4 rB = recL[wave][(prow + 16) * 9 + tap];

        short8 b00 = wf[((2 * tap) * 4 + 0) * 64 + lane];
        short8 b01 = wf[((2 * tap) * 4 + 1) * 64 + lane];
        short8 b02 = wf[((2 * tap) * 4 + 2) * 64 + lane];
        short8 b03 = wf[((2 * tap) * 4 + 3) * 64 + lane];
        short8 b10 = wf[((2 * tap + 1) * 4 + 0) * 64 + lane];
        short8 b11 = wf[((2 * tap + 1) * 4 + 1) * 64 + lane];
        short8 b12 = wf[((2 * tap + 1) * 4 + 2) * 64 + lane];
        short8 b13 = wf[((2 * tap + 1) * 4 + 3) * 64 + lane];

        int iA = rA.x & 0x3FFF, dA = (rA.x >> 14) & 1, yA = ((rA.x >> 15) & 1) << 7;
        int iB = rB.x & 0x3FFF, dB = (rB.x >> 14) & 1, yB = ((rB.x >> 15) & 1) << 7;
        float wA00 = h2f(rA.y), wA01 = h2f((unsigned)rA.y >> 16);
        float wA10 = h2f(rA.z), wA11 = h2f((unsigned)rA.z >> 16);
        float wB00 = h2f(rB.y), wB01 = h2f((unsigned)rB.y >> 16);
        float wB10 = h2f(rB.z), wB11 = h2f((unsigned)rB.z >> 16);

        size_t oA0 = (size_t)iA * 64,           oA1 = (size_t)(iA + dA) * 64;
        size_t oA2 = (size_t)(iA + yA) * 64,    oA3 = (size_t)(iA + yA + dA) * 64;
        size_t oB0 = (size_t)iB * 64,           oB1 = (size_t)(iB + dB) * 64;
        size_t oB2 = (size_t)(iB + yB) * 64,    oB3 = (size_t)(iB + yB + dB) * 64;

        ushort8 A0a = *(const ushort8*)(bp0 + oA0), A1a = *(const ushort8*)(bp0 + oA1);
        ushort8 A2a = *(const ushort8*)(bp0 + oA2), A3a = *(const ushort8*)(bp0 + oA3);
        ushort8 A0b = *(const ushort8*)(bp1 + oA0), A1b = *(const ushort8*)(bp1 + oA1);
        ushort8 A2b = *(const ushort8*)(bp1 + oA2), A3b = *(const ushort8*)(bp1 + oA3);
        ushort8 B0a = *(const ushort8*)(bp0 + oB0), B1a = *(const ushort8*)(bp0 + oB1);
        ushort8 B2a = *(const ushort8*)(bp0 + oB2), B3a = *(const ushort8*)(bp0 + oB3);
        ushort8 B0b = *(const ushort8*)(bp1 + oB0), B1b = *(const ushort8*)(bp1 + oB1);
        ushort8 B2b = *(const ushort8*)(bp1 + oB2), B3b = *(const ushort8*)(bp1 + oB3);

        short8 aA0, aB0, aA1, aB1;
        #pragma unroll
        for (int j = 0; j < 8; ++j) {
            float v0 = wA00 * bf2f(A0a[j]) + wA01 * bf2f(A1a[j])
                     + wA10 * bf2f(A2a[j]) + wA11 * bf2f(A3a[j]);
            float v1 = wA00 * bf2f(A0b[j]) + wA01 * bf2f(A1b[j])
                     + wA10 * bf2f(A2b[j]) + wA11 * bf2f(A3b[j]);
            float u0 = wB00 * bf2f(B0a[j]) + wB01 * bf2f(B1a[j])
                     + wB10 * bf2f(B2a[j]) + wB11 * bf2f(B3a[j]);
            float u1 = wB00 * bf2f(B0b[j]) + wB01 * bf2f(B1b[j])
                     + wB10 * bf2f(B2b[j]) + wB11 * bf2f(B3b[j]);
            aA0[j] = f2bf(v0);  aA1[j] = f2bf(v1);
            aB0[j] = f2bf(u0);  aB1[j] = f2bf(u1);
        }
        accA0 = __builtin_amdgcn_mfma_f32_16x16x32_bf16(aA0, b00, accA0, 0, 0, 0);
        accA1 = __builtin_amdgcn_mfma_f32_16x16x32_bf16(aA0, b01, accA1, 0, 0, 0);
        accA2 = __builtin_amdgcn_mfma_f32_16x16x32_bf16(aA0, b02, accA2, 0, 0, 0);
        accA3 = __builtin_amdgcn_mfma_f32_16x16x32_bf16(aA0, b03, accA3, 0, 0, 0);
        accB0 = __builtin_amdgcn_mfma_f32_16x16x32_bf16(aB0, b00, accB0, 0, 0, 0);
        accB1 = __builtin_amdgcn_mfma_f32_16x16x32_bf16(aB0, b01, accB1, 0, 0, 0);
        accB2 = __builtin_amdgcn_mfma_f32_16x16x32_bf16(aB0, b02, accB2, 0, 0, 0);
        accB3 = __builtin_amdgcn_mfma_f32_16x16x32_bf16(aB0, b03, accB3, 0, 0, 0);
        accA0 = __builtin_amdgcn_mfma_f32_16x16x32_bf16(aA1, b10, accA0, 0, 0, 0);
        accA1 = __builtin_amdgcn_mfma_f32_16x16x32_bf16(aA1, b11, accA1, 0, 0, 0);
        accA2 = __builtin_amdgcn_mfma_f32_16x16x32_bf16(aA1, b12, accA2, 0, 0, 0);
        accA3 = __builtin_amdgcn_mfma_f32_16x16x32_bf16(aA1, b13, accA3, 0, 0, 0);
        accB0 = __builtin_amdgcn_mfma_f32_16x16x32_bf16(aB1, b10, accB0, 0, 0, 0);
        accB1 = __builtin_amdgcn_mfma_f32_16x16x32_bf16(aB1, b11, accB1, 0, 0, 0);
        accB2 = __builtin_amdgcn_mfma_f32_16x16x32_bf16(aB1, b12, accB2, 0, 0, 0);
        accB3 = __builtin_amdgcn_mfma_f32_16x16x32_bf16(aB1, b13, accB3, 0, 0, 0);
    }

    // ---- epilogue: NONTEMPORAL f32x4 stores (keep xT resident in L2) ----
    {
        int ocol = lane & 15;
        int pixA = wave * 32 + khalf * 4;
        float* ob = out + ((size_t)b * COUT) * HW + ho * WW;
        f32x4* dst;
        dst = (f32x4*)(ob + (size_t)(0 * 16 + ocol) * HW + pixA);
        __builtin_nontemporal_store(accA0, dst);
        __builtin_nontemporal_store(accB0, dst + 4);
        dst = (f32x4*)(ob + (size_t)(1 * 16 + ocol) * HW + pixA);
        __builtin_nontemporal_store(accA1, dst);
        __builtin_nontemporal_store(accB1, dst + 4);
        dst = (f32x4*)(ob + (size_t)(2 * 16 + ocol) * HW + pixA);
        __builtin_nontemporal_store(accA2, dst);
        __builtin_nontemporal_store(accB2, dst + 4);
        dst = (f32x4*)(ob + (size_t)(3 * 16 + ocol) * HW + pixA);
        __builtin_nontemporal_store(accA3, dst);
        __builtin_nontemporal_store(accB3, dst + 4);
    }
}

extern "C" void kernel_launch(void* const* d_in, const int* in_sizes, int n_in,
                              void* d_out, int out_size, void* d_ws, size_t ws_size,
                              hipStream_t stream)
{
    const float* x    = (const float*)d_in[0];
    const float* woff = (const float*)d_in[1];
    const float* wdef = (const float*)d_in[2];
    float* out  = (float*)d_out;

    unsigned short* wfrag = (unsigned short*)d_ws;          // 73.7 KB
    unsigned short* wfo   = wfrag + 36864;                  // 36.9 KB
    unsigned short* xT    = wfo + 18432;                    // 16.8 MB

    hipLaunchKernelGGL(to_chlast_k, dim3(BATCH * HH), dim3(256), 0, stream,
                       x, xT);
    hipLaunchKernelGGL(build_wfrag_k, dim3(COUT * 576 / 256), dim3(256), 0, stream,
                       wdef, wfrag);
    hipLaunchKernelGGL(build_wfo_k, dim3(32 * 576 / 256), dim3(256), 0, stream,
                       woff, wfo);
    hipLaunchKernelGGL(deform_fused2_k, dim3(HH * 8), dim3(256), 0, stream,
                       xT, (const short8*)wfo, (const short8*)wfrag, out);
}

// Round 11
// 110.883 us; speedup vs baseline: 1.0834x; 1.0156x over previous
//
#include <hip/hip_runtime.h>
#include <hip/hip_bf16.h>

#define BATCH 8
#define CIN   64
#define COUT  64
#define HH    128
#define WW    128
#define HW    (HH * WW)
#define OFFC  18
#define KK    9

typedef __attribute__((ext_vector_type(8))) short short8;
typedef __attribute__((ext_vector_type(8))) unsigned short ushort8;
typedef __attribute__((ext_vector_type(4))) float f32x4;

__device__ __forceinline__ float bf2f(unsigned short u) {
    return __builtin_bit_cast(float, ((unsigned int)u) << 16);
}
__device__ __forceinline__ short f2bf(float v) {
    __hip_bfloat16 h = __float2bfloat16(v);
    return __builtin_bit_cast(short, h);
}
__device__ __forceinline__ unsigned f2h(float v) {
    return (unsigned)__builtin_bit_cast(unsigned short, (_Float16)v);
}
__device__ __forceinline__ float h2f(unsigned bits) {
    return (float)__builtin_bit_cast(_Float16, (unsigned short)(bits & 0xFFFF));
}

// ------- Kernel X: x (b,c,h,w) f32 -> xT (b,h,w,c) bf16 -------
__global__ __launch_bounds__(256) void to_chlast_k(
    const float* __restrict__ x, unsigned short* __restrict__ xT)
{
    __shared__ unsigned short t[128 * 72];
    int blk = blockIdx.x;                    // ho*8 + b
    int b  = blk & 7;
    int ho = blk >> 3;
    int tid = threadIdx.x;

    const float* xr = x + (size_t)b * CIN * HW + ho * WW;
    for (int i = tid; i < 2048; i += 256) {
        int c = i >> 5, w4 = (i & 31) * 4;
        float4 v = *(const float4*)(xr + (size_t)c * HW + w4);
        t[(w4 + 0) * 72 + c] = (unsigned short)f2bf(v.x);
        t[(w4 + 1) * 72 + c] = (unsigned short)f2bf(v.y);
        t[(w4 + 2) * 72 + c] = (unsigned short)f2bf(v.z);
        t[(w4 + 3) * 72 + c] = (unsigned short)f2bf(v.w);
    }
    __syncthreads();

    unsigned short* orow = xT + (size_t)(b * HH + ho) * WW * 64;
    for (int j = tid; j < 1024; j += 256) {
        int w = j >> 3, c8 = (j & 7) * 8;
        *(ushort8*)(orow + w * 64 + c8) = *(const ushort8*)(t + w * 72 + c8);
    }
}

// ------- Kernel B: w_deform -> bf16 B-fragments wf[kk][nt(4)][lane][8] -------
__global__ __launch_bounds__(256) void build_wfrag_k(
    const float* __restrict__ wd, unsigned short* __restrict__ wf)
{
    int idx = blockIdx.x * 256 + threadIdx.x;
    int ck = idx % 576;
    int o  = idx / 576;
    int c = ck & 63, k = ck >> 6;
    float v = wd[o * 576 + c * 9 + k];
    int kk = ck >> 5, nt = o >> 4;
    int lane = (o & 15) | (((ck >> 3) & 3) << 4);
    int j = ck & 7;
    wf[((kk * 4 + nt) * 64 + lane) * 8 + j] = (unsigned short)f2bf(v);
}

// ------- Kernel B2: w_offset -> bf16 B-fragments wfo[kk][nt(2)][lane][8], N pad 18->32 -------
__global__ __launch_bounds__(256) void build_wfo_k(
    const float* __restrict__ wo, unsigned short* __restrict__ wfo)
{
    int idx = blockIdx.x * 256 + threadIdx.x;
    if (idx >= 32 * 576) return;
    int ck = idx % 576;
    int ov = idx / 576;
    int c = ck & 63, tap = ck >> 6;
    float v = (ov < OFFC) ? wo[ov * 576 + c * 9 + tap] : 0.f;
    int kk = ck >> 5, nt = ov >> 4;
    int lane = (ov & 15) | (((ck >> 3) & 3) << 4);
    int j = ck & 7;
    wfo[((kk * 2 + nt) * 64 + lane) * 8 + j] = (unsigned short)f2bf(v);
}

// ---------------- Kernel C: fused, zero-barrier, TAP-PIPELINED deform conv ----------------
// Structure as R10 (self-contained waves, rec in LDS, nontemporal out) PLUS an explicit
// 1-deep software pipeline over taps: tap t+1's 16 gathers are issued BEFORE tap t's
// convert+MFMA, so L2 latency (~300-600cy) hides under ~600cy of VALU. Double-buffered
// g[2][16] (128 VGPR) + accs + wf ~= 230 VGPR; __launch_bounds__(256,2) pins <=256
// (2 waves/SIMD). Few strong waves > many weak waves: MLP = waves x in-flight loads
// is the metric (R6 vs R10 evidence), and in-flight loads are VGPR-dest-bound.
__global__ __launch_bounds__(256, 2) void deform_fused3_k(
    const unsigned short* __restrict__ xT,
    const short8* __restrict__ wfo,
    const short8* __restrict__ wf, float* __restrict__ out)
{
    __shared__ float offsL[4][32 * 20];     // 10240 B  [wave][pix][20]
    __shared__ int4  recL[4][288];          // 18432 B  [wave][pix*9+tap]

    int tid  = threadIdx.x;
    int blk  = blockIdx.x;                  // ho*8 + b
    int b    = blk & 7;
    int ho   = blk >> 3;

    const unsigned short* pT = xT + (size_t)b * HW * 64;

    int lane  = tid & 63;
    int wave  = tid >> 6;
    int prow  = lane & 15;
    int khalf = lane >> 4;
    int px0   = wave * 32 + prow;
    int px1   = px0 + 16;

    // ---- phase A: offsets = conv3x3(x, w_offset) via MFMA, 2 pixel-tiles ----
    {
        f32x4 oa00 = {0.f,0.f,0.f,0.f}, oa01 = {0.f,0.f,0.f,0.f};
        f32x4 oa10 = {0.f,0.f,0.f,0.f}, oa11 = {0.f,0.f,0.f,0.f};
        #pragma unroll
        for (int kk = 0; kk < 18; ++kk) {
            int tap = kk >> 1;
            int y   = ho + tap / 3 - 1;
            int dx  = tap % 3 - 1;
            int c0  = ((kk & 1) << 5) + (khalf << 3);
            short8 a0 = {0,0,0,0,0,0,0,0};
            short8 a1 = {0,0,0,0,0,0,0,0};
            int xw0 = px0 + dx, xw1 = px1 + dx;
            if ((unsigned)y < HH && (unsigned)xw0 < WW)
                a0 = *(const short8*)(pT + (((size_t)(y * WW + xw0)) << 6) + c0);
            if ((unsigned)y < HH && (unsigned)xw1 < WW)
                a1 = *(const short8*)(pT + (((size_t)(y * WW + xw1)) << 6) + c0);
            short8 b0 = wfo[(kk * 2 + 0) * 64 + lane];
            short8 b1 = wfo[(kk * 2 + 1) * 64 + lane];
            oa00 = __builtin_amdgcn_mfma_f32_16x16x32_bf16(a0, b0, oa00, 0, 0, 0);
            oa01 = __builtin_amdgcn_mfma_f32_16x16x32_bf16(a0, b1, oa01, 0, 0, 0);
            oa10 = __builtin_amdgcn_mfma_f32_16x16x32_bf16(a1, b0, oa10, 0, 0, 0);
            oa11 = __builtin_amdgcn_mfma_f32_16x16x32_bf16(a1, b1, oa11, 0, 0, 0);
        }
        int ocol = lane & 15;
        int pl0  = khalf * 4;
        #pragma unroll
        for (int r = 0; r < 4; ++r) {
            offsL[wave][(pl0 + r) * 20 + ocol]        = oa00[r];
            offsL[wave][(pl0 + 16 + r) * 20 + ocol]   = oa10[r];
        }
        if (ocol < 2) {
            #pragma unroll
            for (int r = 0; r < 4; ++r) {
                offsL[wave][(pl0 + r) * 20 + 16 + ocol]      = oa01[r];
                offsL[wave][(pl0 + 16 + r) * 20 + 16 + ocol] = oa11[r];
            }
        }
    }
    // no barrier: same-wave LDS RAW

    // ---- phase 0: this wave's 32 px x 9 taps -> packed records in LDS ----
    for (int e = lane; e < 288; e += 64) {
        int p = e / 9, k = e - p * 9;
        int wo = wave * 32 + p;
        float dy = offsL[wave][p * 20 + 2 * k];
        float dx = offsL[wave][p * 20 + 2 * k + 1];
        float yy = (float)(ho - 1 + k / 3) + dy;
        float xx = (float)(wo - 1 + k % 3) + dx;
        float y0 = floorf(yy), x0 = floorf(xx);
        float wy1 = yy - y0, wx1 = xx - x0;
        float wy0 = 1.f - wy1, wx0 = 1.f - wx1;
        bool valid = (yy > -1.f) && (yy < (float)HH) && (xx > -1.f) && (xx < (float)WW);
        int y0i = (int)y0, x0i = (int)x0;
        bool iy0 = (unsigned)y0i < HH, iy1 = (unsigned)(y0i + 1) < HH;
        bool ix0 = (unsigned)x0i < WW, ix1 = (unsigned)(x0i + 1) < WW;
        float m00 = (valid && iy0 && ix0) ? 1.f : 0.f;
        float m01 = (valid && iy0 && ix1) ? 1.f : 0.f;
        float m10 = (valid && iy1 && ix0) ? 1.f : 0.f;
        float m11 = (valid && iy1 && ix1) ? 1.f : 0.f;
        int yc0 = min(max(y0i, 0), HH - 1), yc1 = min(max(y0i + 1, 0), HH - 1);
        int xc0 = min(max(x0i, 0), WW - 1), xc1 = min(max(x0i + 1, 0), WW - 1);
        int idx00 = yc0 * WW + xc0;
        int ddx   = xc1 - xc0;
        int dyf   = yc1 - yc0;
        int4 r;
        r.x = idx00 | (ddx << 14) | (dyf << 15);
        r.y = (int)(f2h(wy0 * wx0 * m00) | (f2h(wy0 * wx1 * m01) << 16));
        r.z = (int)(f2h(wy1 * wx0 * m10) | (f2h(wy1 * wx1 * m11) << 16));
        r.w = 0;
        recL[wave][e] = r;
    }
    // no barrier: same-wave producer/consumer

    // ---- phase 1: tap loop, software-pipelined 1 deep ----
    f32x4 accA0 = {0.f,0.f,0.f,0.f}, accA1 = {0.f,0.f,0.f,0.f};
    f32x4 accA2 = {0.f,0.f,0.f,0.f}, accA3 = {0.f,0.f,0.f,0.f};
    f32x4 accB0 = {0.f,0.f,0.f,0.f}, accB1 = {0.f,0.f,0.f,0.f};
    f32x4 accB2 = {0.f,0.f,0.f,0.f}, accB3 = {0.f,0.f,0.f,0.f};

    const unsigned short* bp0 = pT + (khalf << 3);
    const unsigned short* bp1 = bp0 + 32;

    int4    rr[2][2];       // [buf][tileA,tileB]
    ushort8 g[2][16];       // [buf][A0a..A3a, A0b..A3b, B0a..B3a, B0b..B3b]

    // prologue: records + gathers for tap 0
    rr[0][0] = recL[wave][prow * 9];
    rr[0][1] = recL[wave][(prow + 16) * 9];
    {
        int iA = rr[0][0].x & 0x3FFF, dA = (rr[0][0].x >> 14) & 1, yA = ((rr[0][0].x >> 15) & 1) << 7;
        int iB = rr[0][1].x & 0x3FFF, dB = (rr[0][1].x >> 14) & 1, yB = ((rr[0][1].x >> 15) & 1) << 7;
        size_t oA0 = (size_t)iA * 64,        oA1 = (size_t)(iA + dA) * 64;
        size_t oA2 = (size_t)(iA + yA) * 64, oA3 = (size_t)(iA + yA + dA) * 64;
        size_t oB0 = (size_t)iB * 64,        oB1 = (size_t)(iB + dB) * 64;
        size_t oB2 = (size_t)(iB + yB) * 64, oB3 = (size_t)(iB + yB + dB) * 64;
        g[0][0]  = *(const ushort8*)(bp0 + oA0);  g[0][1]  = *(const ushort8*)(bp0 + oA1);
        g[0][2]  = *(const ushort8*)(bp0 + oA2);  g[0][3]  = *(const ushort8*)(bp0 + oA3);
        g[0][4]  = *(const ushort8*)(bp1 + oA0);  g[0][5]  = *(const ushort8*)(bp1 + oA1);
        g[0][6]  = *(const ushort8*)(bp1 + oA2);  g[0][7]  = *(const ushort8*)(bp1 + oA3);
        g[0][8]  = *(const ushort8*)(bp0 + oB0);  g[0][9]  = *(const ushort8*)(bp0 + oB1);
        g[0][10] = *(const ushort8*)(bp0 + oB2);  g[0][11] = *(const ushort8*)(bp0 + oB3);
        g[0][12] = *(const ushort8*)(bp1 + oB0);  g[0][13] = *(const ushort8*)(bp1 + oB1);
        g[0][14] = *(const ushort8*)(bp1 + oB2);  g[0][15] = *(const ushort8*)(bp1 + oB3);
    }

    #pragma unroll
    for (int t = 0; t < 9; ++t) {
        const int cur = t & 1, nxt = cur ^ 1;

        // ---- issue NEXT tap's gathers first (latency hides under this tap's work) ----
        if (t + 1 < 9) {
            rr[nxt][0] = recL[wave][prow * 9 + t + 1];
            rr[nxt][1] = recL[wave][(prow + 16) * 9 + t + 1];
            int iA = rr[nxt][0].x & 0x3FFF, dA = (rr[nxt][0].x >> 14) & 1, yA = ((rr[nxt][0].x >> 15) & 1) << 7;
            int iB = rr[nxt][1].x & 0x3FFF, dB = (rr[nxt][1].x >> 14) & 1, yB = ((rr[nxt][1].x >> 15) & 1) << 7;
            size_t oA0 = (size_t)iA * 64,        oA1 = (size_t)(iA + dA) * 64;
            size_t oA2 = (size_t)(iA + yA) * 64, oA3 = (size_t)(iA + yA + dA) * 64;
            size_t oB0 = (size_t)iB * 64,        oB1 = (size_t)(iB + dB) * 64;
            size_t oB2 = (size_t)(iB + yB) * 64, oB3 = (size_t)(iB + yB + dB) * 64;
            g[nxt][0]  = *(const ushort8*)(bp0 + oA0);  g[nxt][1]  = *(const ushort8*)(bp0 + oA1);
            g[nxt][2]  = *(const ushort8*)(bp0 + oA2);  g[nxt][3]  = *(const ushort8*)(bp0 + oA3);
            g[nxt][4]  = *(const ushort8*)(bp1 + oA0);  g[nxt][5]  = *(const ushort8*)(bp1 + oA1);
            g[nxt][6]  = *(const ushort8*)(bp1 + oA2);  g[nxt][7]  = *(const ushort8*)(bp1 + oA3);
            g[nxt][8]  = *(const ushort8*)(bp0 + oB0);  g[nxt][9]  = *(const ushort8*)(bp0 + oB1);
            g[nxt][10] = *(const ushort8*)(bp0 + oB2);  g[nxt][11] = *(const ushort8*)(bp0 + oB3);
            g[nxt][12] = *(const ushort8*)(bp1 + oB0);  g[nxt][13] = *(const ushort8*)(bp1 + oB1);
            g[nxt][14] = *(const ushort8*)(bp1 + oB2);  g[nxt][15] = *(const ushort8*)(bp1 + oB3);
        }

        // ---- wf fragments for this tap (L1/L2-hot) ----
        short8 b00 = wf[((2 * t) * 4 + 0) * 64 + lane];
        short8 b01 = wf[((2 * t) * 4 + 1) * 64 + lane];
        short8 b02 = wf[((2 * t) * 4 + 2) * 64 + lane];
        short8 b03 = wf[((2 * t) * 4 + 3) * 64 + lane];
        short8 b10 = wf[((2 * t + 1) * 4 + 0) * 64 + lane];
        short8 b11 = wf[((2 * t + 1) * 4 + 1) * 64 + lane];
        short8 b12 = wf[((2 * t + 1) * 4 + 2) * 64 + lane];
        short8 b13 = wf[((2 * t + 1) * 4 + 3) * 64 + lane];

        // ---- convert this tap's gathers (waits vmcnt on g[cur] only) ----
        float wA00 = h2f(rr[cur][0].y), wA01 = h2f((unsigned)rr[cur][0].y >> 16);
        float wA10 = h2f(rr[cur][0].z), wA11 = h2f((unsigned)rr[cur][0].z >> 16);
        float wB00 = h2f(rr[cur][1].y), wB01 = h2f((unsigned)rr[cur][1].y >> 16);
        float wB10 = h2f(rr[cur][1].z), wB11 = h2f((unsigned)rr[cur][1].z >> 16);

        short8 aA0, aA1, aB0, aB1;
        #pragma unroll
        for (int j = 0; j < 8; ++j) {
            float v0 = wA00 * bf2f(g[cur][0][j])  + wA01 * bf2f(g[cur][1][j])
                     + wA10 * bf2f(g[cur][2][j])  + wA11 * bf2f(g[cur][3][j]);
            float v1 = wA00 * bf2f(g[cur][4][j])  + wA01 * bf2f(g[cur][5][j])
                     + wA10 * bf2f(g[cur][6][j])  + wA11 * bf2f(g[cur][7][j]);
            float u0 = wB00 * bf2f(g[cur][8][j])  + wB01 * bf2f(g[cur][9][j])
                     + wB10 * bf2f(g[cur][10][j]) + wB11 * bf2f(g[cur][11][j]);
            float u1 = wB00 * bf2f(g[cur][12][j]) + wB01 * bf2f(g[cur][13][j])
                     + wB10 * bf2f(g[cur][14][j]) + wB11 * bf2f(g[cur][15][j]);
            aA0[j] = f2bf(v0);  aA1[j] = f2bf(v1);
            aB0[j] = f2bf(u0);  aB1[j] = f2bf(u1);
        }
        accA0 = __builtin_amdgcn_mfma_f32_16x16x32_bf16(aA0, b00, accA0, 0, 0, 0);
        accA1 = __builtin_amdgcn_mfma_f32_16x16x32_bf16(aA0, b01, accA1, 0, 0, 0);
        accA2 = __builtin_amdgcn_mfma_f32_16x16x32_bf16(aA0, b02, accA2, 0, 0, 0);
        accA3 = __builtin_amdgcn_mfma_f32_16x16x32_bf16(aA0, b03, accA3, 0, 0, 0);
        accB0 = __builtin_amdgcn_mfma_f32_16x16x32_bf16(aB0, b00, accB0, 0, 0, 0);
        accB1 = __builtin_amdgcn_mfma_f32_16x16x32_bf16(aB0, b01, accB1, 0, 0, 0);
        accB2 = __builtin_amdgcn_mfma_f32_16x16x32_bf16(aB0, b02, accB2, 0, 0, 0);
        accB3 = __builtin_amdgcn_mfma_f32_16x16x32_bf16(aB0, b03, accB3, 0, 0, 0);
        accA0 = __builtin_amdgcn_mfma_f32_16x16x32_bf16(aA1, b10, accA0, 0, 0, 0);
        accA1 = __builtin_amdgcn_mfma_f32_16x16x32_bf16(aA1, b11, accA1, 0, 0, 0);
        accA2 = __builtin_amdgcn_mfma_f32_16x16x32_bf16(aA1, b12, accA2, 0, 0, 0);
        accA3 = __builtin_amdgcn_mfma_f32_16x16x32_bf16(aA1, b13, accA3, 0, 0, 0);
        accB0 = __builtin_amdgcn_mfma_f32_16x16x32_bf16(aB1, b10, accB0, 0, 0, 0);
        accB1 = __builtin_amdgcn_mfma_f32_16x16x32_bf16(aB1, b11, accB1, 0, 0, 0);
        accB2 = __builtin_amdgcn_mfma_f32_16x16x32_bf16(aB1, b12, accB2, 0, 0, 0);
        accB3 = __builtin_amdgcn_mfma_f32_16x16x32_bf16(aB1, b13, accB3, 0, 0, 0);
    }

    // ---- epilogue: NONTEMPORAL f32x4 stores ----
    {
        int ocol = lane & 15;
        int pixA = wave * 32 + khalf * 4;
        float* ob = out + ((size_t)b * COUT) * HW + ho * WW;
        f32x4* dst;
        dst = (f32x4*)(ob + (size_t)(0 * 16 + ocol) * HW + pixA);
        __builtin_nontemporal_store(accA0, dst);
        __builtin_nontemporal_store(accB0, dst + 4);
        dst = (f32x4*)(ob + (size_t)(1 * 16 + ocol) * HW + pixA);
        __builtin_nontemporal_store(accA1, dst);
        __builtin_nontemporal_store(accB1, dst + 4);
        dst = (f32x4*)(ob + (size_t)(2 * 16 + ocol) * HW + pixA);
        __builtin_nontemporal_store(accA2, dst);
        __builtin_nontemporal_store(accB2, dst + 4);
        dst = (f32x4*)(ob + (size_t)(3 * 16 + ocol) * HW + pixA);
        __builtin_nontemporal_store(accA3, dst);
        __builtin_nontemporal_store(accB3, dst + 4);
    }
}

extern "C" void kernel_launch(void* const* d_in, const int* in_sizes, int n_in,
                              void* d_out, int out_size, void* d_ws, size_t ws_size,
                              hipStream_t stream)
{
    const float* x    = (const float*)d_in[0];
    const float* woff = (const float*)d_in[1];
    const float* wdef = (const float*)d_in[2];
    float* out  = (float*)d_out;

    unsigned short* wfrag = (unsigned short*)d_ws;          // 73.7 KB
    unsigned short* wfo   = wfrag + 36864;                  // 36.9 KB
    unsigned short* xT    = wfo + 18432;                    // 16.8 MB

    hipLaunchKernelGGL(to_chlast_k, dim3(BATCH * HH), dim3(256), 0, stream,
                       x, xT);
    hipLaunchKernelGGL(build_wfrag_k, dim3(COUT * 576 / 256), dim3(256), 0, stream,
                       wdef, wfrag);
    hipLaunchKernelGGL(build_wfo_k, dim3(32 * 576 / 256), dim3(256), 0, stream,
                       woff, wfo);
    hipLaunchKernelGGL(deform_fused3_k, dim3(HH * 8), dim3(256), 0, stream,
                       xT, (const short8*)wfo, (const short8*)wfrag, out);
}

// Round 12
// 98.096 us; speedup vs baseline: 1.2246x; 1.1304x over previous
//
#include <hip/hip_runtime.h>
#include <hip/hip_bf16.h>

#define BATCH 8
#define CIN   64
#define COUT  64
#define HH    128
#define WW    128
#define HW    (HH * WW)
#define OFFC  18
#define KK    9
#define NROWS 6
#define ROWB  (WW * 128)          // 16384 B per staged row (128 px x 128 B)

typedef __attribute__((ext_vector_type(8))) short short8;
typedef __attribute__((ext_vector_type(8))) unsigned short ushort8;
typedef __attribute__((ext_vector_type(4))) float f32x4;

__device__ __forceinline__ float bf2f(unsigned short u) {
    return __builtin_bit_cast(float, ((unsigned int)u) << 16);
}
__device__ __forceinline__ short f2bf(float v) {
    __hip_bfloat16 h = __float2bfloat16(v);
    return __builtin_bit_cast(short, h);
}

// ------- Kernel X: x (b,c,h,w) f32 -> xT (b,h,w,c) bf16 -------
__global__ __launch_bounds__(256) void to_chlast_k(
    const float* __restrict__ x, unsigned short* __restrict__ xT)
{
    __shared__ unsigned short t[128 * 72];
    int blk = blockIdx.x;                    // ho*8 + b
    int b  = blk & 7;
    int ho = blk >> 3;
    int tid = threadIdx.x;

    const float* xr = x + (size_t)b * CIN * HW + ho * WW;
    for (int i = tid; i < 2048; i += 256) {
        int c = i >> 5, w4 = (i & 31) * 4;
        float4 v = *(const float4*)(xr + (size_t)c * HW + w4);
        t[(w4 + 0) * 72 + c] = (unsigned short)f2bf(v.x);
        t[(w4 + 1) * 72 + c] = (unsigned short)f2bf(v.y);
        t[(w4 + 2) * 72 + c] = (unsigned short)f2bf(v.z);
        t[(w4 + 3) * 72 + c] = (unsigned short)f2bf(v.w);
    }
    __syncthreads();

    unsigned short* orow = xT + (size_t)(b * HH + ho) * WW * 64;
    for (int j = tid; j < 1024; j += 256) {
        int w = j >> 3, c8 = (j & 7) * 8;
        *(ushort8*)(orow + w * 64 + c8) = *(const ushort8*)(t + w * 72 + c8);
    }
}

// ------- Kernel B: w_deform -> bf16 B-fragments wf[kk][nt(4)][lane][8] -------
__global__ __launch_bounds__(256) void build_wfrag_k(
    const float* __restrict__ wd, unsigned short* __restrict__ wf)
{
    int idx = blockIdx.x * 256 + threadIdx.x;
    int ck = idx % 576;
    int o  = idx / 576;
    int c = ck & 63, k = ck >> 6;
    float v = wd[o * 576 + c * 9 + k];
    int kk = ck >> 5, nt = o >> 4;
    int lane = (o & 15) | (((ck >> 3) & 3) << 4);
    int j = ck & 7;
    wf[((kk * 4 + nt) * 64 + lane) * 8 + j] = (unsigned short)f2bf(v);
}

// ------- Kernel B2: w_offset -> bf16 B-fragments wfo[kk][nt(2)][lane][8], N pad 18->32 -------
__global__ __launch_bounds__(256) void build_wfo_k(
    const float* __restrict__ wo, unsigned short* __restrict__ wfo)
{
    int idx = blockIdx.x * 256 + threadIdx.x;
    if (idx >= 32 * 576) return;
    int ck = idx % 576;
    int ov = idx / 576;
    int c = ck & 63, tap = ck >> 6;
    float v = (ov < OFFC) ? wo[ov * 576 + c * 9 + tap] : 0.f;
    int kk = ck >> 5, nt = ov >> 4;
    int lane = (ov & 15) | (((ck >> 3) & 3) << 4);
    int j = ck & 7;
    wfo[((kk * 2 + nt) * 64 + lane) * 8 + j] = (unsigned short)f2bf(v);
}

// ---------------- Kernel C: LDS-staged-gather fused deform conv ----------------
// R11 analysis: ~100us floor = L2 request parallelism (256 x 64B requests/wave/tap,
// ~300cy latency, ~64 outstanding/CU). Fix: stage rows ho-2..ho+3 (96KB bf16) in LDS,
// gather via ds_read_b128 (12cy issue ~= latency -> no pipelining needed). >=96% of
// corners are in-tile (offsets ~N(0,0.5)); rare rows fall back to exec-masked global
// loads of the SAME xT bytes (bit-identical). XOR-swizzle slot^(px&7) on 16B chunks
// breaks the record-base bank-0 alignment (write & read use same involution).
// One __syncthreads (after stage); everything else wave-private. 1 block/CU by LDS.
__global__ __launch_bounds__(256, 1) void deform_fused4_k(
    const unsigned short* __restrict__ xT,
    const short8* __restrict__ wfo,
    const short8* __restrict__ wf, float* __restrict__ out)
{
    __shared__ char  stage[NROWS * ROWB];   // 98304 B
    __shared__ float offsL[4][32 * 20];     // 10240 B

    int tid  = threadIdx.x;
    int blk  = blockIdx.x;                  // ho*8 + b
    int b    = blk & 7;
    int ho   = blk >> 3;
    int row_lo = ho - 2;                    // tile rows row_lo .. row_lo+5 (abs, may be OOB)

    const unsigned short* pT = xT + (size_t)b * HW * 64;

    int lane  = tid & 63;
    int wave  = tid >> 6;
    int prow  = lane & 15;
    int khalf = lane >> 4;
    int px0   = wave * 32 + prow;
    int px1   = px0 + 16;

    // ---- STAGE: rows row_lo..row_lo+5 of xT[b] -> swizzled LDS ----
    for (int c = tid; c < NROWS * 1024; c += 256) {     // 1024 16B-chunks per row
        int r  = c >> 10;
        int ar = row_lo + r;
        if ((unsigned)ar < (unsigned)HH) {
            int px   = (c >> 3) & 127;
            int slot = c & 7;
            ushort8 v = *(const ushort8*)(pT + (((size_t)ar * WW + px) << 6) + slot * 8);
            *(ushort8*)(stage + r * ROWB + px * 128 + ((slot ^ (px & 7)) << 4)) = v;
        }
    }
    __syncthreads();

    auto LRD = [&](int r, int xc, int slot) -> ushort8 {
        return *(const ushort8*)(stage + r * ROWB + xc * 128 + ((slot ^ (xc & 7)) << 4));
    };
    auto GRD = [&](int idx, int h) -> ushort8 {
        return *(const ushort8*)(pT + ((size_t)idx << 6) + (khalf << 3) + h * 32);
    };

    // ---- phase A: offsets = conv3x3(x, w_offset) via MFMA from the LDS stage ----
    {
        f32x4 oa00 = {0.f,0.f,0.f,0.f}, oa01 = {0.f,0.f,0.f,0.f};
        f32x4 oa10 = {0.f,0.f,0.f,0.f}, oa11 = {0.f,0.f,0.f,0.f};
        #pragma unroll
        for (int kk = 0; kk < 18; ++kk) {
            int tap = kk >> 1;
            int y   = ho + tap / 3 - 1;
            int dx  = tap % 3 - 1;
            int slot = khalf + (kk & 1) * 4;
            short8 a0 = {0,0,0,0,0,0,0,0};
            short8 a1 = {0,0,0,0,0,0,0,0};
            int xw0 = px0 + dx, xw1 = px1 + dx;
            if ((unsigned)y < HH) {
                int ry = y - row_lo;        // always in [1,3]
                if ((unsigned)xw0 < WW) a0 = __builtin_bit_cast(short8, LRD(ry, xw0, slot));
                if ((unsigned)xw1 < WW) a1 = __builtin_bit_cast(short8, LRD(ry, xw1, slot));
            }
            short8 b0 = wfo[(kk * 2 + 0) * 64 + lane];
            short8 b1 = wfo[(kk * 2 + 1) * 64 + lane];
            oa00 = __builtin_amdgcn_mfma_f32_16x16x32_bf16(a0, b0, oa00, 0, 0, 0);
            oa01 = __builtin_amdgcn_mfma_f32_16x16x32_bf16(a0, b1, oa01, 0, 0, 0);
            oa10 = __builtin_amdgcn_mfma_f32_16x16x32_bf16(a1, b0, oa10, 0, 0, 0);
            oa11 = __builtin_amdgcn_mfma_f32_16x16x32_bf16(a1, b1, oa11, 0, 0, 0);
        }
        int ocol = lane & 15;
        int pl0  = khalf * 4;
        #pragma unroll
        for (int r = 0; r < 4; ++r) {
            offsL[wave][(pl0 + r) * 20 + ocol]      = oa00[r];
            offsL[wave][(pl0 + 16 + r) * 20 + ocol] = oa10[r];
        }
        if (ocol < 2) {
            #pragma unroll
            for (int r = 0; r < 4; ++r) {
                offsL[wave][(pl0 + r) * 20 + 16 + ocol]      = oa01[r];
                offsL[wave][(pl0 + 16 + r) * 20 + 16 + ocol] = oa11[r];
            }
        }
    }
    // no barrier: offsL slice is wave-private (wave-lockstep ordering)

    // ---- tap loop: inline positions + LDS gather (+rare global fallback) + MFMA ----
    f32x4 accA0 = {0.f,0.f,0.f,0.f}, accA1 = {0.f,0.f,0.f,0.f};
    f32x4 accA2 = {0.f,0.f,0.f,0.f}, accA3 = {0.f,0.f,0.f,0.f};
    f32x4 accB0 = {0.f,0.f,0.f,0.f}, accB1 = {0.f,0.f,0.f,0.f};
    f32x4 accB2 = {0.f,0.f,0.f,0.f}, accB3 = {0.f,0.f,0.f,0.f};

    #pragma unroll
    for (int t = 0; t < 9; ++t) {
        // B-fragments for this tap (global, L1/L2-hot, same for all waves)
        short8 b00 = wf[((2 * t) * 4 + 0) * 64 + lane];
        short8 b01 = wf[((2 * t) * 4 + 1) * 64 + lane];
        short8 b02 = wf[((2 * t) * 4 + 2) * 64 + lane];
        short8 b03 = wf[((2 * t) * 4 + 3) * 64 + lane];
        short8 b10 = wf[((2 * t + 1) * 4 + 0) * 64 + lane];
        short8 b11 = wf[((2 * t + 1) * 4 + 1) * 64 + lane];
        short8 b12 = wf[((2 * t + 1) * 4 + 2) * 64 + lane];
        short8 b13 = wf[((2 * t + 1) * 4 + 3) * 64 + lane];

        // ---------- tile A positions ----------
        float dyA = offsL[wave][prow * 20 + 2 * t];
        float dxA = offsL[wave][prow * 20 + 2 * t + 1];
        float yyA = (float)(ho - 1 + t / 3) + dyA;
        float xxA = (float)(px0 - 1 + t % 3) + dxA;
        float y0A = floorf(yyA), x0A = floorf(xxA);
        float wy1A = yyA - y0A, wx1A = xxA - x0A;
        float wy0A = 1.f - wy1A, wx0A = 1.f - wx1A;
        bool vA = (yyA > -1.f) && (yyA < (float)HH) && (xxA > -1.f) && (xxA < (float)WW);
        int y0iA = (int)y0A, x0iA = (int)x0A;
        bool iy0A = (unsigned)y0iA < HH, iy1A = (unsigned)(y0iA + 1) < HH;
        bool ix0A = (unsigned)x0iA < WW, ix1A = (unsigned)(x0iA + 1) < WW;
        float wA00 = wy0A * wx0A * ((vA && iy0A && ix0A) ? 1.f : 0.f);
        float wA01 = wy0A * wx1A * ((vA && iy0A && ix1A) ? 1.f : 0.f);
        float wA10 = wy1A * wx0A * ((vA && iy1A && ix0A) ? 1.f : 0.f);
        float wA11 = wy1A * wx1A * ((vA && iy1A && ix1A) ? 1.f : 0.f);
        int yc0A = min(max(y0iA, 0), HH - 1), yc1A = min(max(y0iA + 1, 0), HH - 1);
        int xc0A = min(max(x0iA, 0), WW - 1), xc1A = min(max(x0iA + 1, 0), WW - 1);

        // ---------- tile B positions ----------
        float dyB = offsL[wave][(prow + 16) * 20 + 2 * t];
        float dxB = offsL[wave][(prow + 16) * 20 + 2 * t + 1];
        float yyB = (float)(ho - 1 + t / 3) + dyB;
        float xxB = (float)(px1 - 1 + t % 3) + dxB;
        float y0B = floorf(yyB), x0B = floorf(xxB);
        float wy1B = yyB - y0B, wx1B = xxB - x0B;
        float wy0B = 1.f - wy1B, wx0B = 1.f - wx1B;
        bool vB = (yyB > -1.f) && (yyB < (float)HH) && (xxB > -1.f) && (xxB < (float)WW);
        int y0iB = (int)y0B, x0iB = (int)x0B;
        bool iy0B = (unsigned)y0iB < HH, iy1B = (unsigned)(y0iB + 1) < HH;
        bool ix0B = (unsigned)x0iB < WW, ix1B = (unsigned)(x0iB + 1) < WW;
        float wB00 = wy0B * wx0B * ((vB && iy0B && ix0B) ? 1.f : 0.f);
        float wB01 = wy0B * wx1B * ((vB && iy0B && ix1B) ? 1.f : 0.f);
        float wB10 = wy1B * wx0B * ((vB && iy1B && ix0B) ? 1.f : 0.f);
        float wB11 = wy1B * wx1B * ((vB && iy1B && ix1B) ? 1.f : 0.f);
        int yc0B = min(max(y0iB, 0), HH - 1), yc1B = min(max(y0iB + 1, 0), HH - 1);
        int xc0B = min(max(x0iB, 0), WW - 1), xc1B = min(max(x0iB + 1, 0), WW - 1);

        // ---------- LDS gathers (ds_read_b128), clamped row index ----------
        int ry0A = yc0A - row_lo, ry1A = yc1A - row_lo;
        int ry0B = yc0B - row_lo, ry1B = yc1B - row_lo;
        int r0A = min(max(ry0A, 0), NROWS - 1), r1A = min(max(ry1A, 0), NROWS - 1);
        int r0B = min(max(ry0B, 0), NROWS - 1), r1B = min(max(ry1B, 0), NROWS - 1);

        ushort8 A0a = LRD(r0A, xc0A, khalf),     A0b = LRD(r0A, xc0A, khalf + 4);
        ushort8 A1a = LRD(r0A, xc1A, khalf),     A1b = LRD(r0A, xc1A, khalf + 4);
        ushort8 A2a = LRD(r1A, xc0A, khalf),     A2b = LRD(r1A, xc0A, khalf + 4);
        ushort8 A3a = LRD(r1A, xc1A, khalf),     A3b = LRD(r1A, xc1A, khalf + 4);
        ushort8 B0a = LRD(r0B, xc0B, khalf),     B0b = LRD(r0B, xc0B, khalf + 4);
        ushort8 B1a = LRD(r0B, xc1B, khalf),     B1b = LRD(r0B, xc1B, khalf + 4);
        ushort8 B2a = LRD(r1B, xc0B, khalf),     B2b = LRD(r1B, xc0B, khalf + 4);
        ushort8 B3a = LRD(r1B, xc1B, khalf),     B3b = LRD(r1B, xc1B, khalf + 4);

        // ---------- rare out-of-tile fallbacks (same bytes from global) ----------
        if ((unsigned)ry0A >= (unsigned)NROWS) {
            A0a = GRD(yc0A * WW + xc0A, 0);  A0b = GRD(yc0A * WW + xc0A, 1);
            A1a = GRD(yc0A * WW + xc1A, 0);  A1b = GRD(yc0A * WW + xc1A, 1);
        }
        if ((unsigned)ry1A >= (unsigned)NROWS) {
            A2a = GRD(yc1A * WW + xc0A, 0);  A2b = GRD(yc1A * WW + xc0A, 1);
            A3a = GRD(yc1A * WW + xc1A, 0);  A3b = GRD(yc1A * WW + xc1A, 1);
        }
        if ((unsigned)ry0B >= (unsigned)NROWS) {
            B0a = GRD(yc0B * WW + xc0B, 0);  B0b = GRD(yc0B * WW + xc0B, 1);
            B1a = GRD(yc0B * WW + xc1B, 0);  B1b = GRD(yc0B * WW + xc1B, 1);
        }
        if ((unsigned)ry1B >= (unsigned)NROWS) {
            B2a = GRD(yc1B * WW + xc0B, 0);  B2b = GRD(yc1B * WW + xc0B, 1);
            B3a = GRD(yc1B * WW + xc1B, 0);  B3b = GRD(yc1B * WW + xc1B, 1);
        }

        // ---------- interpolate + convert ----------
        short8 aA0, aA1, aB0, aB1;
        #pragma unroll
        for (int j = 0; j < 8; ++j) {
            float v0 = wA00 * bf2f(A0a[j]) + wA01 * bf2f(A1a[j])
                     + wA10 * bf2f(A2a[j]) + wA11 * bf2f(A3a[j]);
            float v1 = wA00 * bf2f(A0b[j]) + wA01 * bf2f(A1b[j])
                     + wA10 * bf2f(A2b[j]) + wA11 * bf2f(A3b[j]);
            float u0 = wB00 * bf2f(B0a[j]) + wB01 * bf2f(B1a[j])
                     + wB10 * bf2f(B2a[j]) + wB11 * bf2f(B3a[j]);
            float u1 = wB00 * bf2f(B0b[j]) + wB01 * bf2f(B1b[j])
                     + wB10 * bf2f(B2b[j]) + wB11 * bf2f(B3b[j]);
            aA0[j] = f2bf(v0);  aA1[j] = f2bf(v1);
            aB0[j] = f2bf(u0);  aB1[j] = f2bf(u1);
        }
        accA0 = __builtin_amdgcn_mfma_f32_16x16x32_bf16(aA0, b00, accA0, 0, 0, 0);
        accA1 = __builtin_amdgcn_mfma_f32_16x16x32_bf16(aA0, b01, accA1, 0, 0, 0);
        accA2 = __builtin_amdgcn_mfma_f32_16x16x32_bf16(aA0, b02, accA2, 0, 0, 0);
        accA3 = __builtin_amdgcn_mfma_f32_16x16x32_bf16(aA0, b03, accA3, 0, 0, 0);
        accB0 = __builtin_amdgcn_mfma_f32_16x16x32_bf16(aB0, b00, accB0, 0, 0, 0);
        accB1 = __builtin_amdgcn_mfma_f32_16x16x32_bf16(aB0, b01, accB1, 0, 0, 0);
        accB2 = __builtin_amdgcn_mfma_f32_16x16x32_bf16(aB0, b02, accB2, 0, 0, 0);
        accB3 = __builtin_amdgcn_mfma_f32_16x16x32_bf16(aB0, b03, accB3, 0, 0, 0);
        accA0 = __builtin_amdgcn_mfma_f32_16x16x32_bf16(aA1, b10, accA0, 0, 0, 0);
        accA1 = __builtin_amdgcn_mfma_f32_16x16x32_bf16(aA1, b11, accA1, 0, 0, 0);
        accA2 = __builtin_amdgcn_mfma_f32_16x16x32_bf16(aA1, b12, accA2, 0, 0, 0);
        accA3 = __builtin_amdgcn_mfma_f32_16x16x32_bf16(aA1, b13, accA3, 0, 0, 0);
        accB0 = __builtin_amdgcn_mfma_f32_16x16x32_bf16(aB1, b10, accB0, 0, 0, 0);
        accB1 = __builtin_amdgcn_mfma_f32_16x16x32_bf16(aB1, b11, accB1, 0, 0, 0);
        accB2 = __builtin_amdgcn_mfma_f32_16x16x32_bf16(aB1, b12, accB2, 0, 0, 0);
        accB3 = __builtin_amdgcn_mfma_f32_16x16x32_bf16(aB1, b13, accB3, 0, 0, 0);
    }

    // ---- epilogue: NONTEMPORAL f32x4 stores (lane holds 4 consecutive pixels per o) ----
    {
        int ocol = lane & 15;
        int pixA = wave * 32 + khalf * 4;
        float* ob = out + ((size_t)b * COUT) * HW + ho * WW;
        f32x4* dst;
        dst = (f32x4*)(ob + (size_t)(0 * 16 + ocol) * HW + pixA);
        __builtin_nontemporal_store(accA0, dst);
        __builtin_nontemporal_store(accB0, dst + 4);
        dst = (f32x4*)(ob + (size_t)(1 * 16 + ocol) * HW + pixA);
        __builtin_nontemporal_store(accA1, dst);
        __builtin_nontemporal_store(accB1, dst + 4);
        dst = (f32x4*)(ob + (size_t)(2 * 16 + ocol) * HW + pixA);
        __builtin_nontemporal_store(accA2, dst);
        __builtin_nontemporal_store(accB2, dst + 4);
        dst = (f32x4*)(ob + (size_t)(3 * 16 + ocol) * HW + pixA);
        __builtin_nontemporal_store(accA3, dst);
        __builtin_nontemporal_store(accB3, dst + 4);
    }
}

extern "C" void kernel_launch(void* const* d_in, const int* in_sizes, int n_in,
                              void* d_out, int out_size, void* d_ws, size_t ws_size,
                              hipStream_t stream)
{
    const float* x    = (const float*)d_in[0];
    const float* woff = (const float*)d_in[1];
    const float* wdef = (const float*)d_in[2];
    float* out  = (float*)d_out;

    unsigned short* wfrag = (unsigned short*)d_ws;          // 73.7 KB
    unsigned short* wfo   = wfrag + 36864;                  // 36.9 KB
    unsigned short* xT    = wfo + 18432;                    // 16.8 MB

    hipLaunchKernelGGL(to_chlast_k, dim3(BATCH * HH), dim3(256), 0, stream,
                       x, xT);
    hipLaunchKernelGGL(build_wfrag_k, dim3(COUT * 576 / 256), dim3(256), 0, stream,
                       wdef, wfrag);
    hipLaunchKernelGGL(build_wfo_k, dim3(32 * 576 / 256), dim3(256), 0, stream,
                       woff, wfo);
    hipLaunchKernelGGL(deform_fused4_k, dim3(HH * 8), dim3(256), 0, stream,
                       xT, (const short8*)wfo, (const short8*)wfrag, out);
}

// Round 13
// 67.336 us; speedup vs baseline: 1.7841x; 1.4568x over previous
//
#include <hip/hip_runtime.h>
#include <hip/hip_bf16.h>

#define BATCH 8
#define CIN   64
#define COUT  64
#define HH    128
#define WW    128
#define HW    (HH * WW)
#define OFFC  18
#define KK    9
#define NROWS 7
#define ROWB  (WW * 128)          // 16384 B per staged row (128 px x 128 B)

typedef __attribute__((ext_vector_type(8))) short short8;
typedef __attribute__((ext_vector_type(8))) unsigned short ushort8;
typedef __attribute__((ext_vector_type(4))) float f32x4;

__device__ __forceinline__ float bf2f(unsigned short u) {
    return __builtin_bit_cast(float, ((unsigned int)u) << 16);
}
__device__ __forceinline__ short f2bf(float v) {
    __hip_bfloat16 h = __float2bfloat16(v);
    return __builtin_bit_cast(short, h);
}

// ------- Kernel X: x (b,c,h,w) f32 -> xT (b,h,w,c) bf16 -------
__global__ __launch_bounds__(256) void to_chlast_k(
    const float* __restrict__ x, unsigned short* __restrict__ xT)
{
    __shared__ unsigned short t[128 * 72];
    int blk = blockIdx.x;                    // ho*8 + b
    int b  = blk & 7;
    int ho = blk >> 3;
    int tid = threadIdx.x;

    const float* xr = x + (size_t)b * CIN * HW + ho * WW;
    for (int i = tid; i < 2048; i += 256) {
        int c = i >> 5, w4 = (i & 31) * 4;
        float4 v = *(const float4*)(xr + (size_t)c * HW + w4);
        t[(w4 + 0) * 72 + c] = (unsigned short)f2bf(v.x);
        t[(w4 + 1) * 72 + c] = (unsigned short)f2bf(v.y);
        t[(w4 + 2) * 72 + c] = (unsigned short)f2bf(v.z);
        t[(w4 + 3) * 72 + c] = (unsigned short)f2bf(v.w);
    }
    __syncthreads();

    unsigned short* orow = xT + (size_t)(b * HH + ho) * WW * 64;
    for (int j = tid; j < 1024; j += 256) {
        int w = j >> 3, c8 = (j & 7) * 8;
        *(ushort8*)(orow + w * 64 + c8) = *(const ushort8*)(t + w * 72 + c8);
    }
}

// ------- Kernel B: w_deform -> bf16 B-fragments wf[kk][nt(4)][lane][8] -------
__global__ __launch_bounds__(256) void build_wfrag_k(
    const float* __restrict__ wd, unsigned short* __restrict__ wf)
{
    int idx = blockIdx.x * 256 + threadIdx.x;
    int ck = idx % 576;
    int o  = idx / 576;
    int c = ck & 63, k = ck >> 6;
    float v = wd[o * 576 + c * 9 + k];
    int kk = ck >> 5, nt = o >> 4;
    int lane = (o & 15) | (((ck >> 3) & 3) << 4);
    int j = ck & 7;
    wf[((kk * 4 + nt) * 64 + lane) * 8 + j] = (unsigned short)f2bf(v);
}

// ------- Kernel B2: w_offset -> bf16 B-fragments wfo[kk][nt(2)][lane][8], N pad 18->32 -------
__global__ __launch_bounds__(256) void build_wfo_k(
    const float* __restrict__ wo, unsigned short* __restrict__ wfo)
{
    int idx = blockIdx.x * 256 + threadIdx.x;
    if (idx >= 32 * 576) return;
    int ck = idx % 576;
    int ov = idx / 576;
    int c = ck & 63, tap = ck >> 6;
    float v = (ov < OFFC) ? wo[ov * 576 + c * 9 + tap] : 0.f;
    int kk = ck >> 5, nt = ov >> 4;
    int lane = (ov & 15) | (((ck >> 3) & 3) << 4);
    int j = ck & 7;
    wfo[((kk * 2 + nt) * 64 + lane) * 8 + j] = (unsigned short)f2bf(v);
}

// ---------------- Kernel C: LDS-staged gather, 2-ROW / 512-THREAD blocks ----------------
// R12 fix target: occupancy was 1 wave/SIMD (108.5KB LDS, 256 thr) -> all ds_read /
// convert latency exposed (VALUBusy 32%). Now: 512 threads (8 waves = 2/SIMD), TWO
// output rows per block sharing ONE 7-row stage (ho0-2..ho0+4, 112KB; rows overlap
// so staging per output row ~halves). Waves 0-3 -> row ho0, waves 4-7 -> ho0+1,
// each wave-private otherwise. One barrier (post-stage). Clamped coords are always
// staged (clamp[0,127] subset of staged rows when in-tile); rare out-of-tile rows
// take exec-masked global fallback of the SAME xT bytes (bit-identical).
__global__ __launch_bounds__(512, 1) void deform_fused5_k(
    const unsigned short* __restrict__ xT,
    const short8* __restrict__ wfo,
    const short8* __restrict__ wf, float* __restrict__ out)
{
    __shared__ char  stage[NROWS * ROWB];   // 114688 B
    __shared__ float offsL[8][32 * 20];     // 20480 B  (total 135168 B)

    int tid  = threadIdx.x;
    int blk  = blockIdx.x;                  // rowpair*8 + b
    int b    = blk & 7;
    int ho0  = (blk >> 3) * 2;
    int row_lo = ho0 - 2;                   // staged rows row_lo .. row_lo+6

    const unsigned short* pT = xT + (size_t)b * HW * 64;

    int lane  = tid & 63;
    int wave  = tid >> 6;                   // 0..7
    int wl    = wave & 3;                   // wave-in-rowgroup
    int ho    = ho0 + (wave >> 2);          // this wave's output row
    int prow  = lane & 15;
    int khalf = lane >> 4;
    int px0   = wl * 32 + prow;
    int px1   = px0 + 16;

    // ---- STAGE: rows row_lo..row_lo+6 of xT[b] -> swizzled LDS (512 threads) ----
    for (int c = tid; c < NROWS * 1024; c += 512) {     // 1024 16B-chunks per row
        int r  = c >> 10;
        int ar = row_lo + r;
        if ((unsigned)ar < (unsigned)HH) {
            int px   = (c >> 3) & 127;
            int slot = c & 7;
            ushort8 v = *(const ushort8*)(pT + (((size_t)ar * WW + px) << 6) + slot * 8);
            *(ushort8*)(stage + r * ROWB + px * 128 + ((slot ^ (px & 7)) << 4)) = v;
        }
    }
    __syncthreads();

    auto LRD = [&](int r, int xc, int slot) -> ushort8 {
        return *(const ushort8*)(stage + r * ROWB + xc * 128 + ((slot ^ (xc & 7)) << 4));
    };
    auto GRD = [&](int idx, int h) -> ushort8 {
        return *(const ushort8*)(pT + ((size_t)idx << 6) + (khalf << 3) + h * 32);
    };

    // ---- phase A: offsets = conv3x3(x, w_offset) via MFMA from the LDS stage ----
    {
        f32x4 oa00 = {0.f,0.f,0.f,0.f}, oa01 = {0.f,0.f,0.f,0.f};
        f32x4 oa10 = {0.f,0.f,0.f,0.f}, oa11 = {0.f,0.f,0.f,0.f};
        #pragma unroll
        for (int kk = 0; kk < 18; ++kk) {
            int tap = kk >> 1;
            int y   = ho + tap / 3 - 1;
            int dx  = tap % 3 - 1;
            int slot = khalf + (kk & 1) * 4;
            short8 a0 = {0,0,0,0,0,0,0,0};
            short8 a1 = {0,0,0,0,0,0,0,0};
            int xw0 = px0 + dx, xw1 = px1 + dx;
            if ((unsigned)y < HH) {
                int ry = y - row_lo;        // in [1,4], always staged
                if ((unsigned)xw0 < WW) a0 = __builtin_bit_cast(short8, LRD(ry, xw0, slot));
                if ((unsigned)xw1 < WW) a1 = __builtin_bit_cast(short8, LRD(ry, xw1, slot));
            }
            short8 b0 = wfo[(kk * 2 + 0) * 64 + lane];
            short8 b1 = wfo[(kk * 2 + 1) * 64 + lane];
            oa00 = __builtin_amdgcn_mfma_f32_16x16x32_bf16(a0, b0, oa00, 0, 0, 0);
            oa01 = __builtin_amdgcn_mfma_f32_16x16x32_bf16(a0, b1, oa01, 0, 0, 0);
            oa10 = __builtin_amdgcn_mfma_f32_16x16x32_bf16(a1, b0, oa10, 0, 0, 0);
            oa11 = __builtin_amdgcn_mfma_f32_16x16x32_bf16(a1, b1, oa11, 0, 0, 0);
        }
        int ocol = lane & 15;
        int pl0  = khalf * 4;
        #pragma unroll
        for (int r = 0; r < 4; ++r) {
            offsL[wave][(pl0 + r) * 20 + ocol]      = oa00[r];
            offsL[wave][(pl0 + 16 + r) * 20 + ocol] = oa10[r];
        }
        if (ocol < 2) {
            #pragma unroll
            for (int r = 0; r < 4; ++r) {
                offsL[wave][(pl0 + r) * 20 + 16 + ocol]      = oa01[r];
                offsL[wave][(pl0 + 16 + r) * 20 + 16 + ocol] = oa11[r];
            }
        }
    }
    // no barrier: offsL slice is wave-private

    // ---- tap loop: inline positions + LDS gather (+rare global fallback) + MFMA ----
    f32x4 accA0 = {0.f,0.f,0.f,0.f}, accA1 = {0.f,0.f,0.f,0.f};
    f32x4 accA2 = {0.f,0.f,0.f,0.f}, accA3 = {0.f,0.f,0.f,0.f};
    f32x4 accB0 = {0.f,0.f,0.f,0.f}, accB1 = {0.f,0.f,0.f,0.f};
    f32x4 accB2 = {0.f,0.f,0.f,0.f}, accB3 = {0.f,0.f,0.f,0.f};

    #pragma unroll
    for (int t = 0; t < 9; ++t) {
        short8 b00 = wf[((2 * t) * 4 + 0) * 64 + lane];
        short8 b01 = wf[((2 * t) * 4 + 1) * 64 + lane];
        short8 b02 = wf[((2 * t) * 4 + 2) * 64 + lane];
        short8 b03 = wf[((2 * t) * 4 + 3) * 64 + lane];
        short8 b10 = wf[((2 * t + 1) * 4 + 0) * 64 + lane];
        short8 b11 = wf[((2 * t + 1) * 4 + 1) * 64 + lane];
        short8 b12 = wf[((2 * t + 1) * 4 + 2) * 64 + lane];
        short8 b13 = wf[((2 * t + 1) * 4 + 3) * 64 + lane];

        // ---------- tile A positions ----------
        float dyA = offsL[wave][prow * 20 + 2 * t];
        float dxA = offsL[wave][prow * 20 + 2 * t + 1];
        float yyA = (float)(ho - 1 + t / 3) + dyA;
        float xxA = (float)(px0 - 1 + t % 3) + dxA;
        float y0A = floorf(yyA), x0A = floorf(xxA);
        float wy1A = yyA - y0A, wx1A = xxA - x0A;
        float wy0A = 1.f - wy1A, wx0A = 1.f - wx1A;
        bool vA = (yyA > -1.f) && (yyA < (float)HH) && (xxA > -1.f) && (xxA < (float)WW);
        int y0iA = (int)y0A, x0iA = (int)x0A;
        bool iy0A = (unsigned)y0iA < HH, iy1A = (unsigned)(y0iA + 1) < HH;
        bool ix0A = (unsigned)x0iA < WW, ix1A = (unsigned)(x0iA + 1) < WW;
        float wA00 = wy0A * wx0A * ((vA && iy0A && ix0A) ? 1.f : 0.f);
        float wA01 = wy0A * wx1A * ((vA && iy0A && ix1A) ? 1.f : 0.f);
        float wA10 = wy1A * wx0A * ((vA && iy1A && ix0A) ? 1.f : 0.f);
        float wA11 = wy1A * wx1A * ((vA && iy1A && ix1A) ? 1.f : 0.f);
        int yc0A = min(max(y0iA, 0), HH - 1), yc1A = min(max(y0iA + 1, 0), HH - 1);
        int xc0A = min(max(x0iA, 0), WW - 1), xc1A = min(max(x0iA + 1, 0), WW - 1);

        // ---------- tile B positions ----------
        float dyB = offsL[wave][(prow + 16) * 20 + 2 * t];
        float dxB = offsL[wave][(prow + 16) * 20 + 2 * t + 1];
        float yyB = (float)(ho - 1 + t / 3) + dyB;
        float xxB = (float)(px1 - 1 + t % 3) + dxB;
        float y0B = floorf(yyB), x0B = floorf(xxB);
        float wy1B = yyB - y0B, wx1B = xxB - x0B;
        float wy0B = 1.f - wy1B, wx0B = 1.f - wx1B;
        bool vB = (yyB > -1.f) && (yyB < (float)HH) && (xxB > -1.f) && (xxB < (float)WW);
        int y0iB = (int)y0B, x0iB = (int)x0B;
        bool iy0B = (unsigned)y0iB < HH, iy1B = (unsigned)(y0iB + 1) < HH;
        bool ix0B = (unsigned)x0iB < WW, ix1B = (unsigned)(x0iB + 1) < WW;
        float wB00 = wy0B * wx0B * ((vB && iy0B && ix0B) ? 1.f : 0.f);
        float wB01 = wy0B * wx1B * ((vB && iy0B && ix1B) ? 1.f : 0.f);
        float wB10 = wy1B * wx0B * ((vB && iy1B && ix0B) ? 1.f : 0.f);
        float wB11 = wy1B * wx1B * ((vB && iy1B && ix1B) ? 1.f : 0.f);
        int yc0B = min(max(y0iB, 0), HH - 1), yc1B = min(max(y0iB + 1, 0), HH - 1);
        int xc0B = min(max(x0iB, 0), WW - 1), xc1B = min(max(x0iB + 1, 0), WW - 1);

        // ---------- LDS gathers (ds_read_b128), clamped row index ----------
        int ry0A = yc0A - row_lo, ry1A = yc1A - row_lo;
        int ry0B = yc0B - row_lo, ry1B = yc1B - row_lo;
        int r0A = min(max(ry0A, 0), NROWS - 1), r1A = min(max(ry1A, 0), NROWS - 1);
        int r0B = min(max(ry0B, 0), NROWS - 1), r1B = min(max(ry1B, 0), NROWS - 1);

        ushort8 A0a = LRD(r0A, xc0A, khalf),     A0b = LRD(r0A, xc0A, khalf + 4);
        ushort8 A1a = LRD(r0A, xc1A, khalf),     A1b = LRD(r0A, xc1A, khalf + 4);
        ushort8 A2a = LRD(r1A, xc0A, khalf),     A2b = LRD(r1A, xc0A, khalf + 4);
        ushort8 A3a = LRD(r1A, xc1A, khalf),     A3b = LRD(r1A, xc1A, khalf + 4);
        ushort8 B0a = LRD(r0B, xc0B, khalf),     B0b = LRD(r0B, xc0B, khalf + 4);
        ushort8 B1a = LRD(r0B, xc1B, khalf),     B1b = LRD(r0B, xc1B, khalf + 4);
        ushort8 B2a = LRD(r1B, xc0B, khalf),     B2b = LRD(r1B, xc0B, khalf + 4);
        ushort8 B3a = LRD(r1B, xc1B, khalf),     B3b = LRD(r1B, xc1B, khalf + 4);

        // ---------- rare out-of-tile fallbacks (same bytes from global) ----------
        if ((unsigned)ry0A >= (unsigned)NROWS) {
            A0a = GRD(yc0A * WW + xc0A, 0);  A0b = GRD(yc0A * WW + xc0A, 1);
            A1a = GRD(yc0A * WW + xc1A, 0);  A1b = GRD(yc0A * WW + xc1A, 1);
        }
        if ((unsigned)ry1A >= (unsigned)NROWS) {
            A2a = GRD(yc1A * WW + xc0A, 0);  A2b = GRD(yc1A * WW + xc0A, 1);
            A3a = GRD(yc1A * WW + xc1A, 0);  A3b = GRD(yc1A * WW + xc1A, 1);
        }
        if ((unsigned)ry0B >= (unsigned)NROWS) {
            B0a = GRD(yc0B * WW + xc0B, 0);  B0b = GRD(yc0B * WW + xc0B, 1);
            B1a = GRD(yc0B * WW + xc1B, 0);  B1b = GRD(yc0B * WW + xc1B, 1);
        }
        if ((unsigned)ry1B >= (unsigned)NROWS) {
            B2a = GRD(yc1B * WW + xc0B, 0);  B2b = GRD(yc1B * WW + xc0B, 1);
            B3a = GRD(yc1B * WW + xc1B, 0);  B3b = GRD(yc1B * WW + xc1B, 1);
        }

        // ---------- interpolate + convert ----------
        short8 aA0, aA1, aB0, aB1;
        #pragma unroll
        for (int j = 0; j < 8; ++j) {
            float v0 = wA00 * bf2f(A0a[j]) + wA01 * bf2f(A1a[j])
                     + wA10 * bf2f(A2a[j]) + wA11 * bf2f(A3a[j]);
            float v1 = wA00 * bf2f(A0b[j]) + wA01 * bf2f(A1b[j])
                     + wA10 * bf2f(A2b[j]) + wA11 * bf2f(A3b[j]);
            float u0 = wB00 * bf2f(B0a[j]) + wB01 * bf2f(B1a[j])
                     + wB10 * bf2f(B2a[j]) + wB11 * bf2f(B3a[j]);
            float u1 = wB00 * bf2f(B0b[j]) + wB01 * bf2f(B1b[j])
                     + wB10 * bf2f(B2b[j]) + wB11 * bf2f(B3b[j]);
            aA0[j] = f2bf(v0);  aA1[j] = f2bf(v1);
            aB0[j] = f2bf(u0);  aB1[j] = f2bf(u1);
        }
        accA0 = __builtin_amdgcn_mfma_f32_16x16x32_bf16(aA0, b00, accA0, 0, 0, 0);
        accA1 = __builtin_amdgcn_mfma_f32_16x16x32_bf16(aA0, b01, accA1, 0, 0, 0);
        accA2 = __builtin_amdgcn_mfma_f32_16x16x32_bf16(aA0, b02, accA2, 0, 0, 0);
        accA3 = __builtin_amdgcn_mfma_f32_16x16x32_bf16(aA0, b03, accA3, 0, 0, 0);
        accB0 = __builtin_amdgcn_mfma_f32_16x16x32_bf16(aB0, b00, accB0, 0, 0, 0);
        accB1 = __builtin_amdgcn_mfma_f32_16x16x32_bf16(aB0, b01, accB1, 0, 0, 0);
        accB2 = __builtin_amdgcn_mfma_f32_16x16x32_bf16(aB0, b02, accB2, 0, 0, 0);
        accB3 = __builtin_amdgcn_mfma_f32_16x16x32_bf16(aB0, b03, accB3, 0, 0, 0);
        accA0 = __builtin_amdgcn_mfma_f32_16x16x32_bf16(aA1, b10, accA0, 0, 0, 0);
        accA1 = __builtin_amdgcn_mfma_f32_16x16x32_bf16(aA1, b11, accA1, 0, 0, 0);
        accA2 = __builtin_amdgcn_mfma_f32_16x16x32_bf16(aA1, b12, accA2, 0, 0, 0);
        accA3 = __builtin_amdgcn_mfma_f32_16x16x32_bf16(aA1, b13, accA3, 0, 0, 0);
        accB0 = __builtin_amdgcn_mfma_f32_16x16x32_bf16(aB1, b10, accB0, 0, 0, 0);
        accB1 = __builtin_amdgcn_mfma_f32_16x16x32_bf16(aB1, b11, accB1, 0, 0, 0);
        accB2 = __builtin_amdgcn_mfma_f32_16x16x32_bf16(aB1, b12, accB2, 0, 0, 0);
        accB3 = __builtin_amdgcn_mfma_f32_16x16x32_bf16(aB1, b13, accB3, 0, 0, 0);
    }

    // ---- epilogue: NONTEMPORAL f32x4 stores (lane holds 4 consecutive pixels per o) ----
    {
        int ocol = lane & 15;
        int pixA = wl * 32 + khalf * 4;
        float* ob = out + ((size_t)b * COUT) * HW + ho * WW;
        f32x4* dst;
        dst = (f32x4*)(ob + (size_t)(0 * 16 + ocol) * HW + pixA);
        __builtin_nontemporal_store(accA0, dst);
        __builtin_nontemporal_store(accB0, dst + 4);
        dst = (f32x4*)(ob + (size_t)(1 * 16 + ocol) * HW + pixA);
        __builtin_nontemporal_store(accA1, dst);
        __builtin_nontemporal_store(accB1, dst + 4);
        dst = (f32x4*)(ob + (size_t)(2 * 16 + ocol) * HW + pixA);
        __builtin_nontemporal_store(accA2, dst);
        __builtin_nontemporal_store(accB2, dst + 4);
        dst = (f32x4*)(ob + (size_t)(3 * 16 + ocol) * HW + pixA);
        __builtin_nontemporal_store(accA3, dst);
        __builtin_nontemporal_store(accB3, dst + 4);
    }
}

extern "C" void kernel_launch(void* const* d_in, const int* in_sizes, int n_in,
                              void* d_out, int out_size, void* d_ws, size_t ws_size,
                              hipStream_t stream)
{
    const float* x    = (const float*)d_in[0];
    const float* woff = (const float*)d_in[1];
    const float* wdef = (const float*)d_in[2];
    float* out  = (float*)d_out;

    unsigned short* wfrag = (unsigned short*)d_ws;          // 73.7 KB
    unsigned short* wfo   = wfrag + 36864;                  // 36.9 KB
    unsigned short* xT    = wfo + 18432;                    // 16.8 MB

    hipLaunchKernelGGL(to_chlast_k, dim3(BATCH * HH), dim3(256), 0, stream,
                       x, xT);
    hipLaunchKernelGGL(build_wfrag_k, dim3(COUT * 576 / 256), dim3(256), 0, stream,
                       wdef, wfrag);
    hipLaunchKernelGGL(build_wfo_k, dim3(32 * 576 / 256), dim3(256), 0, stream,
                       woff, wfo);
    hipLaunchKernelGGL(deform_fused5_k, dim3((HH / 2) * 8), dim3(512), 0, stream,
                       xT, (const short8*)wfo, (const short8*)wfrag, out);
}